// Round 13
// baseline (711.691 us; speedup 1.0000x reference)
//
#include <hip/hip_runtime.h>
#include <hip/hip_bf16.h>

#define HD 64

typedef unsigned short u16;

__device__ __forceinline__ float lrelu(float x) { return x > 0.f ? x : 0.2f * x; }
__device__ __forceinline__ int clampi(int v, int maxv) {
    return v < 0 ? 0 : (v >= maxv ? maxv - 1 : v);
}
__device__ __forceinline__ float bf2f(u16 u) {
    return __uint_as_float(((unsigned int)u) << 16);
}
// round-to-nearest-even fp32 -> bf16 (bit-level; inputs are finite)
__device__ __forceinline__ u16 f2bf(float f) {
    unsigned int u = __float_as_uint(f);
    unsigned int lsb = (u >> 16) & 1u;
    u += 0x7fffu + lsb;
    return (u16)(u >> 16);
}

// ---------------- init: zero deg/cursor/pooled/gcnt ----------------
__global__ void k_init(int* deg, int* cursor, int* gcnt, float* pooled, int N, int B) {
    int i = blockIdx.x * blockDim.x + threadIdx.x;
    if (i < N) { deg[i] = 0; cursor[i] = 0; }
    if (i < B) gcnt[i] = 0;
    if (i < B * HD) pooled[i] = 0.f;
}

// ---------------- h = relu(x @ node_W + node_b),  x:[N,3] W:[3,64] ----------------
__global__ void k_node_emb(const float* __restrict__ x, const float* __restrict__ W,
                           const float* __restrict__ b, float* __restrict__ h, int N) {
    int i = blockIdx.x * blockDim.x + threadIdx.x;
    if (i >= N * HD) return;
    int n = i >> 6, c = i & 63;
    float acc = b[c];
    acc = fmaf(x[n * 3 + 0], W[0 * HD + c], acc);
    acc = fmaf(x[n * 3 + 1], W[1 * HD + c], acc);
    acc = fmaf(x[n * 3 + 2], W[2 * HD + c], acc);
    h[i] = fmaxf(acc, 0.f);
}

// ---------------- degree histogram over dst ----------------
__global__ void k_deg(const int* __restrict__ dst, int* __restrict__ deg, int E, int N) {
    int e = blockIdx.x * blockDim.x + threadIdx.x;
    if (e < E) atomicAdd(&deg[clampi(dst[e], N)], 1);
}

// ---------------- exclusive prefix sum -> row_ptr (1 block, 1024 threads) ----------------
__global__ void k_scan(const int* __restrict__ deg, int* __restrict__ row_ptr, int N) {
    __shared__ int s[1024];
    int tid = threadIdx.x;
    int base = 0;
    if (tid == 0) row_ptr[0] = 0;
    for (int chunk = 0; chunk < N; chunk += 1024) {
        int i = chunk + tid;
        int v = (i < N) ? deg[i] : 0;
        s[tid] = v;
        __syncthreads();
        for (int off = 1; off < 1024; off <<= 1) {
            int t = (tid >= off) ? s[tid - off] : 0;
            __syncthreads();
            s[tid] += t;
            __syncthreads();
        }
        if (i < N) row_ptr[i + 1] = base + s[tid];
        base += s[1023];
        __syncthreads();
    }
}

// ---------------- CSR scatter; also records inverse map e -> csr position ----------------
__global__ void k_csr(const int* __restrict__ src, const int* __restrict__ dst,
                      const int* __restrict__ row_ptr, int* __restrict__ cursor,
                      int* __restrict__ csr_src, int* __restrict__ csr_eid,
                      int* __restrict__ inv, int E, int N) {
    int e = blockIdx.x * blockDim.x + threadIdx.x;
    if (e >= E) return;
    int d = clampi(dst[e], N);
    int pos = row_ptr[d] + atomicAdd(&cursor[d], 1);
    if (pos < E) { csr_src[pos] = clampi(src[e], N); csr_eid[pos] = e; inv[e] = pos; }
}

// ---------------- graph node counts — LDS histogram ----------------
#define MAXB 2048
__global__ void k_gse(const int* __restrict__ batch, int* __restrict__ gcnt, int N, int B) {
    __shared__ int s_cnt[MAXB];
    int t = threadIdx.x;
    int Bc = B < MAXB ? B : MAXB;
    for (int i = t; i < Bc; i += blockDim.x) s_cnt[i] = 0;
    __syncthreads();
    int n = blockIdx.x * blockDim.x + t;
    if (n < N) {
        int b = clampi(batch[n], B);
        if (b < MAXB) atomicAdd(&s_cnt[b], 1);
        else atomicAdd(&gcnt[b], 1);
    }
    __syncthreads();
    for (int i = t; i < Bc; i += blockDim.x)
        if (s_cnt[i] != 0) atomicAdd(&gcnt[i], s_cnt[i]);
}

// ---------------- ea_self[n,:] = mean of relu(edge_attr@eemb_W+b) over incoming ----------------
__global__ __launch_bounds__(256) void k_eaself(
    const float* __restrict__ edge_attr, const float* __restrict__ eW,
    const float* __restrict__ eB, const int* __restrict__ row_ptr,
    const int* __restrict__ csr_eid, float* __restrict__ ea_self, int N) {
    int wave = threadIdx.x >> 6, lane = threadIdx.x & 63;
    int n = blockIdx.x * 4 + wave;
    if (n >= N) return;
    float w0 = eW[0 * HD + lane], w1 = eW[1 * HD + lane];
    float w2 = eW[2 * HD + lane], w3 = eW[3 * HD + lane];
    float bb = eB[lane];
    int r0 = row_ptr[n], r1 = row_ptr[n + 1];
    float acc = 0.f;
    for (int j = r0; j < r1; j++) {
        int e = csr_eid[j];
        float a0 = edge_attr[e * 4 + 0], a1 = edge_attr[e * 4 + 1];
        float a2 = edge_attr[e * 4 + 2], a3 = edge_attr[e * 4 + 3];
        float v = fmaf(a0, w0, fmaf(a1, w1, fmaf(a2, w2, fmaf(a3, w3, bb))));
        acc += fmaxf(v, 0.f);
    }
    ea_self[n * HD + lane] = acc / fmaxf((float)(r1 - r0), 1.f);
}

// ---------------- per-layer: xp = h@W, 8 nodes per block; zeroes den ----------------
__global__ __launch_bounds__(256) void k_xp(
    const float* __restrict__ h, const float* __restrict__ W,
    const float* __restrict__ asrc, const float* __restrict__ adst,
    u16* __restrict__ xp, float* __restrict__ a_s, float* __restrict__ a_d,
    float* __restrict__ den, int N) {
    __shared__ float hs[8 * HD];
    int n0 = blockIdx.x * 8;
    int t = threadIdx.x;
    for (int i = t; i < 8 * HD; i += 256) {
        int nn = n0 + (i >> 6);
        hs[i] = (nn < N) ? h[(size_t)nn * HD + (i & 63)] : 0.f;
    }
    __syncthreads();
    int c = t;
    float acc[8];
    #pragma unroll
    for (int k = 0; k < 8; k++) acc[k] = 0.f;
    for (int d = 0; d < HD; d++) {
        float wv = W[d * 256 + c];
        #pragma unroll
        for (int k = 0; k < 8; k++) acc[k] = fmaf(hs[k * HD + d], wv, acc[k]);
    }
    float as_ = asrc[c], ad_ = adst[c];
    int hh = c >> 6, cc = c & 63;
    #pragma unroll
    for (int k = 0; k < 8; k++) {
        int nn = n0 + k;
        float ps = acc[k] * as_;
        float pd = acc[k] * ad_;
        #pragma unroll
        for (int o = 32; o > 0; o >>= 1) {
            ps += __shfl_xor(ps, o);
            pd += __shfl_xor(pd, o);
        }
        if (nn < N) {
            xp[(size_t)nn * 256 + c] = f2bf(acc[k]);
            if (cc == 0) {
                a_s[nn * 4 + hh] = ps;
                a_d[nn * 4 + hh] = pd;
                den[nn * 4 + hh] = 0.f;
            }
        }
    }
}

// ---------------- per-layer: edge-parallel attention weights ----------------
// For each edge: a_ed (edge-embedding dot), alpha = lrelu(a_s[src]+a_d[dst]+a_ed),
// w = exp(alpha). Stores w into wcsr at CSR position (via inv[]), accumulates
// den[dst] with atomics (~16 adds/address). Self loops (items E..E+N) use ea_self,
// stored at wcsr[E+n]; their den contribution is added in k_gat (no atomic needed).
__global__ __launch_bounds__(256) void k_aedw(
    const float* __restrict__ edge_attr, const float* __restrict__ eW,
    const float* __restrict__ eB, const float* __restrict__ We,
    const float* __restrict__ ae, const float* __restrict__ ea_self,
    const int* __restrict__ src, const int* __restrict__ dst,
    const int* __restrict__ inv, const float* __restrict__ a_s,
    const float* __restrict__ a_d, float* __restrict__ wcsr,
    float* __restrict__ den, int E, int N) {
    __shared__ float s_wred[256];  // [h*64+d] = sum_c We[d,h*64+c] * ae[h,c]
    __shared__ float s_ew[256];    // [k*64+d]
    __shared__ float s_eb[64];
    int t = threadIdx.x;
    {
        int h = t >> 6, d = t & 63;
        float acc = 0.f;
        for (int c = 0; c < 64; c++)
            acc = fmaf(We[d * 256 + h * 64 + c], ae[h * 64 + c], acc);
        s_wred[t] = acc;
        s_ew[t] = eW[t];
        if (t < 64) s_eb[t] = eB[t];
    }
    __syncthreads();
    int item = blockIdx.x * blockDim.x + t;
    if (item < E) {
        float a0 = edge_attr[item * 4 + 0], a1 = edge_attr[item * 4 + 1];
        float a2 = edge_attr[item * 4 + 2], a3 = edge_attr[item * 4 + 3];
        float h0 = 0.f, h1 = 0.f, h2 = 0.f, h3 = 0.f;
        for (int d = 0; d < HD; d++) {
            float v = fmaf(a0, s_ew[d], fmaf(a1, s_ew[64 + d],
                      fmaf(a2, s_ew[128 + d], fmaf(a3, s_ew[192 + d], s_eb[d]))));
            v = fmaxf(v, 0.f);
            h0 = fmaf(v, s_wred[d], h0);
            h1 = fmaf(v, s_wred[64 + d], h1);
            h2 = fmaf(v, s_wred[128 + d], h2);
            h3 = fmaf(v, s_wred[192 + d], h3);
        }
        int s = clampi(src[item], N), d = clampi(dst[item], N);
        float4 as4 = *(const float4*)(a_s + s * 4);
        float4 ad4 = *(const float4*)(a_d + d * 4);
        float w0 = __expf(lrelu(as4.x + ad4.x + h0));
        float w1 = __expf(lrelu(as4.y + ad4.y + h1));
        float w2 = __expf(lrelu(as4.z + ad4.z + h2));
        float w3 = __expf(lrelu(as4.w + ad4.w + h3));
        int pos = inv[item];
        *(float4*)(wcsr + (size_t)pos * 4) = make_float4(w0, w1, w2, w3);
        atomicAdd(&den[d * 4 + 0], w0);
        atomicAdd(&den[d * 4 + 1], w1);
        atomicAdd(&den[d * 4 + 2], w2);
        atomicAdd(&den[d * 4 + 3], w3);
    } else if (item < E + N) {
        int n = item - E;
        float h0 = 0.f, h1 = 0.f, h2 = 0.f, h3 = 0.f;
        for (int d = 0; d < HD; d++) {
            float v = ea_self[n * HD + d];
            h0 = fmaf(v, s_wred[d], h0);
            h1 = fmaf(v, s_wred[64 + d], h1);
            h2 = fmaf(v, s_wred[128 + d], h2);
            h3 = fmaf(v, s_wred[192 + d], h3);
        }
        float4 as4 = *(const float4*)(a_s + n * 4);
        float4 ad4 = *(const float4*)(a_d + n * 4);
        float w0 = __expf(lrelu(as4.x + ad4.x + h0));
        float w1 = __expf(lrelu(as4.y + ad4.y + h1));
        float w2 = __expf(lrelu(as4.z + ad4.z + h2));
        float w3 = __expf(lrelu(as4.w + ad4.w + h3));
        *(float4*)(wcsr + (size_t)(E + n) * 4) = make_float4(w0, w1, w2, w3);
    }
}

// ---------------- per-layer GAT aggregate: sequential weights + xp gather only ----
// Loop body: sequential csr_src[j]/wcsr[j] + one random bf16 row gather + 4 FMA.
// Gathers across iterations are independent -> overlappable in-flight.
__global__ __launch_bounds__(256) void k_gat(
    const u16* __restrict__ xp, const float* __restrict__ wcsr,
    const float* __restrict__ den, const int* __restrict__ row_ptr,
    const int* __restrict__ csr_src, const float* __restrict__ convb,
    float* __restrict__ h_out, int N, int E) {
    int wave = threadIdx.x >> 6, lane = threadIdx.x & 63;
    int n = blockIdx.x * 4 + wave;
    if (n >= N) return;
    int r0 = row_ptr[n], r1 = row_ptr[n + 1];
    int hl = lane >> 4;
    float wself = wcsr[(size_t)(E + n) * 4 + hl];
    float dtot = den[n * 4 + hl] + wself;
    ushort4 xv4 = *(const ushort4*)(xp + (size_t)n * 256 + lane * 4);
    float acc0 = wself * bf2f(xv4.x), acc1 = wself * bf2f(xv4.y);
    float acc2 = wself * bf2f(xv4.z), acc3 = wself * bf2f(xv4.w);
    for (int j = r0; j < r1; j++) {
        int s = csr_src[j];
        float w = wcsr[(size_t)j * 4 + hl];
        ushort4 x4 = *(const ushort4*)(xp + (size_t)s * 256 + lane * 4);
        acc0 = fmaf(w, bf2f(x4.x), acc0);
        acc1 = fmaf(w, bf2f(x4.y), acc1);
        acc2 = fmaf(w, bf2f(x4.z), acc2);
        acc3 = fmaf(w, bf2f(x4.w), acc3);
    }
    float invd = 1.f / dtot;
    acc0 *= invd; acc1 *= invd; acc2 *= invd; acc3 *= invd;
    // mean over heads
    acc0 += __shfl_xor(acc0, 16); acc0 += __shfl_xor(acc0, 32);
    acc1 += __shfl_xor(acc1, 16); acc1 += __shfl_xor(acc1, 32);
    acc2 += __shfl_xor(acc2, 16); acc2 += __shfl_xor(acc2, 32);
    acc3 += __shfl_xor(acc3, 16); acc3 += __shfl_xor(acc3, 32);
    if (lane < 16) {
        int c = lane * 4;
        h_out[(size_t)n * HD + c + 0] = fmaxf(0.25f * acc0 + convb[c + 0], 0.f);
        h_out[(size_t)n * HD + c + 1] = fmaxf(0.25f * acc1 + convb[c + 1], 0.f);
        h_out[(size_t)n * HD + c + 2] = fmaxf(0.25f * acc2 + convb[c + 2], 0.f);
        h_out[(size_t)n * HD + c + 3] = fmaxf(0.25f * acc3 + convb[c + 3], 0.f);
    }
}

// ---------------- global pool, node-parallel with atomics ----------------
__global__ void k_pool(const float* __restrict__ h, const int* __restrict__ batch,
                       float* __restrict__ pooled, int N, int B) {
    int i = blockIdx.x * blockDim.x + threadIdx.x;
    if (i >= N * HD) return;
    int n = i >> 6, c = i & 63;
    int b = clampi(batch[n], B);
    atomicAdd(&pooled[b * HD + c], h[i]);
}

// ---------------- final MLP (fp32 out; divides pooled sum by count) ----------------
__global__ void k_mlp(const float* __restrict__ u, const float* __restrict__ gW,
                      const float* __restrict__ gb, const float* __restrict__ pooled,
                      const int* __restrict__ gcnt, const float* __restrict__ f1W,
                      const float* __restrict__ f1b, const float* __restrict__ f2W,
                      const float* __restrict__ f2b, float* __restrict__ out, int B) {
    __shared__ float z[2 * HD];
    __shared__ float z1s[HD];
    int b = blockIdx.x, t = threadIdx.x;  // 64 threads
    float acc = gb[t];
    for (int k = 0; k < 10; k++) acc = fmaf(u[b * 10 + k], gW[k * HD + t], acc);
    z[HD + t] = fmaxf(acc, 0.f);
    float invc = 1.f / fmaxf((float)gcnt[b], 1.f);
    z[t] = pooled[b * HD + t] * invc;
    __syncthreads();
    float a1 = f1b[t];
    for (int k = 0; k < 2 * HD; k++) a1 = fmaf(z[k], f1W[k * HD + t], a1);
    z1s[t] = fmaxf(a1, 0.f);
    __syncthreads();
    if (t < 2) {
        float o = f2b[t];
        for (int k = 0; k < HD; k++) o = fmaf(z1s[k], f2W[k * 2 + t], o);
        out[b * 2 + t] = o;
    }
}

extern "C" void kernel_launch(void* const* d_in, const int* in_sizes, int n_in,
                              void* d_out, int out_size, void* d_ws, size_t ws_size,
                              hipStream_t stream) {
    const float* x         = (const float*)d_in[0];
    const int*   ei        = (const int*)d_in[1];
    const float* edge_attr = (const float*)d_in[2];
    const float* u         = (const float*)d_in[3];
    const int*   batch     = (const int*)d_in[4];
    const float* node_W    = (const float*)d_in[5];
    const float* node_b    = (const float*)d_in[6];
    const float* eemb_W    = (const float*)d_in[7];
    const float* eemb_b    = (const float*)d_in[8];
    const float* lin_W     = (const float*)d_in[9];
    const float* att_src   = (const float*)d_in[10];
    const float* att_dst   = (const float*)d_in[11];
    const float* lin_eW    = (const float*)d_in[12];
    const float* att_e     = (const float*)d_in[13];
    const float* conv_b    = (const float*)d_in[14];
    const float* gW        = (const float*)d_in[15];
    const float* gb        = (const float*)d_in[16];
    const float* f1W       = (const float*)d_in[17];
    const float* f1b       = (const float*)d_in[18];
    const float* f2W       = (const float*)d_in[19];
    const float* f2b       = (const float*)d_in[20];

    const int N = in_sizes[0] / 3;
    const int E = in_sizes[2] / 4;
    const int B = in_sizes[3] / 10;
    const int* src = ei;
    const int* dst = ei + E;

    // workspace carve (fp32 then bf16 then ints)
    float* wsf = (float*)d_ws;
    float* h       = wsf;              wsf += (size_t)N * HD;
    float* a_s     = wsf;              wsf += (size_t)N * 4;
    float* a_d     = wsf;              wsf += (size_t)N * 4;
    float* den     = wsf;              wsf += (size_t)N * 4;
    float* ea_self = wsf;              wsf += (size_t)N * HD;
    float* wcsr    = wsf;              wsf += (size_t)(E + N) * 4;
    float* pooled  = wsf;              wsf += (size_t)B * HD;
    u16* xp = (u16*)wsf;               wsf += (size_t)N * 128;   // N*256 bf16
    int* wsi = (int*)wsf;
    int* deg     = wsi;                wsi += N;
    int* row_ptr = wsi;                wsi += N + 1;
    int* cursor  = wsi;                wsi += N;
    int* csr_src = wsi;                wsi += E;
    int* csr_eid = wsi;                wsi += E;
    int* inv     = wsi;                wsi += E;
    int* gcnt    = wsi;                wsi += B;

    k_init<<<(N + 255) / 256, 256, 0, stream>>>(deg, cursor, gcnt, pooled, N, B);
    k_node_emb<<<(N * HD + 255) / 256, 256, 0, stream>>>(x, node_W, node_b, h, N);
    k_deg<<<(E + 255) / 256, 256, 0, stream>>>(dst, deg, E, N);
    k_scan<<<1, 1024, 0, stream>>>(deg, row_ptr, N);
    k_csr<<<(E + 255) / 256, 256, 0, stream>>>(src, dst, row_ptr, cursor, csr_src, csr_eid,
                                               inv, E, N);
    k_gse<<<(N + 255) / 256, 256, 0, stream>>>(batch, gcnt, N, B);
    k_eaself<<<(N + 3) / 4, 256, 0, stream>>>(edge_attr, eemb_W, eemb_b, row_ptr, csr_eid,
                                              ea_self, N);
    for (int i = 0; i < 3; i++) {
        k_xp<<<(N + 7) / 8, 256, 0, stream>>>(h, lin_W + (size_t)i * HD * 256,
                                              att_src + (size_t)i * 256,
                                              att_dst + (size_t)i * 256,
                                              xp, a_s, a_d, den, N);
        k_aedw<<<(E + N + 255) / 256, 256, 0, stream>>>(
            edge_attr, eemb_W, eemb_b, lin_eW + (size_t)i * HD * 256,
            att_e + (size_t)i * 256, ea_self, src, dst, inv, a_s, a_d, wcsr, den, E, N);
        k_gat<<<(N + 3) / 4, 256, 0, stream>>>(xp, wcsr, den, row_ptr, csr_src,
                                               conv_b + (size_t)i * HD, h, N, E);
    }
    k_pool<<<(N * HD + 255) / 256, 256, 0, stream>>>(h, batch, pooled, N, B);
    k_mlp<<<B, 64, 0, stream>>>(u, gW, gb, pooled, gcnt, f1W, f1b, f2W, f2b,
                                (float*)d_out, B);
}

// Round 14
// 522.987 us; speedup vs baseline: 1.3608x; 1.3608x over previous
//
#include <hip/hip_runtime.h>
#include <hip/hip_bf16.h>

#define HD 64

typedef unsigned short u16;

__device__ __forceinline__ float lrelu(float x) { return x > 0.f ? x : 0.2f * x; }
__device__ __forceinline__ int clampi(int v, int maxv) {
    return v < 0 ? 0 : (v >= maxv ? maxv - 1 : v);
}
__device__ __forceinline__ float bf2f(u16 u) {
    return __uint_as_float(((unsigned int)u) << 16);
}
// round-to-nearest-even fp32 -> bf16 (bit-level; inputs are finite)
__device__ __forceinline__ u16 f2bf(float f) {
    unsigned int u = __float_as_uint(f);
    unsigned int lsb = (u >> 16) & 1u;
    u += 0x7fffu + lsb;
    return (u16)(u >> 16);
}

// ---------------- init: zero deg/cursor/pooled/gcnt ----------------
__global__ void k_init(int* deg, int* cursor, int* gcnt, float* pooled, int N, int B) {
    int i = blockIdx.x * blockDim.x + threadIdx.x;
    if (i < N) { deg[i] = 0; cursor[i] = 0; }
    if (i < B) gcnt[i] = 0;
    if (i < B * HD) pooled[i] = 0.f;
}

// ---------------- h = relu(x @ node_W + node_b),  x:[N,3] W:[3,64] ----------------
__global__ void k_node_emb(const float* __restrict__ x, const float* __restrict__ W,
                           const float* __restrict__ b, float* __restrict__ h, int N) {
    int i = blockIdx.x * blockDim.x + threadIdx.x;
    if (i >= N * HD) return;
    int n = i >> 6, c = i & 63;
    float acc = b[c];
    acc = fmaf(x[n * 3 + 0], W[0 * HD + c], acc);
    acc = fmaf(x[n * 3 + 1], W[1 * HD + c], acc);
    acc = fmaf(x[n * 3 + 2], W[2 * HD + c], acc);
    h[i] = fmaxf(acc, 0.f);
}

// ---------------- degree histogram over dst ----------------
__global__ void k_deg(const int* __restrict__ dst, int* __restrict__ deg, int E, int N) {
    int e = blockIdx.x * blockDim.x + threadIdx.x;
    if (e < E) atomicAdd(&deg[clampi(dst[e], N)], 1);
}

// ---------------- hierarchical scan (replaces single-block k_scan) ----------------
// scan1: per-block inclusive scan of deg -> tmp, block totals -> bsum
__global__ void k_scan1(const int* __restrict__ deg, int* __restrict__ tmp,
                        int* __restrict__ bsum, int N) {
    __shared__ int s[256];
    int tid = threadIdx.x;
    int i = blockIdx.x * 256 + tid;
    int v = (i < N) ? deg[i] : 0;
    s[tid] = v;
    __syncthreads();
    for (int off = 1; off < 256; off <<= 1) {
        int t = (tid >= off) ? s[tid - off] : 0;
        __syncthreads();
        s[tid] += t;
        __syncthreads();
    }
    if (i < N) tmp[i] = s[tid];
    if (tid == 255) bsum[blockIdx.x] = s[255];
}
// scan2: exclusive scan of block sums (1 block, up to 1024 blocks' worth)
__global__ void k_scan2(const int* __restrict__ bsum, int* __restrict__ boff, int nb) {
    __shared__ int s[1024];
    int tid = threadIdx.x;
    int v = (tid < nb) ? bsum[tid] : 0;
    s[tid] = v;
    __syncthreads();
    for (int off = 1; off < 1024; off <<= 1) {
        int t = (tid >= off) ? s[tid - off] : 0;
        __syncthreads();
        s[tid] += t;
        __syncthreads();
    }
    if (tid < nb) boff[tid] = s[tid] - v;   // exclusive
}
// scan3: row_ptr[i+1] = tmp[i] + boff[block(i)]
__global__ void k_scan3(const int* __restrict__ tmp, const int* __restrict__ boff,
                        int* __restrict__ row_ptr, int N) {
    int i = blockIdx.x * blockDim.x + threadIdx.x;
    if (i == 0) row_ptr[0] = 0;
    if (i < N) row_ptr[i + 1] = tmp[i] + boff[i >> 8];
}

// ---------------- CSR scatter; stores src, dst, eid per csr slot ----------------
__global__ void k_csr(const int* __restrict__ src, const int* __restrict__ dst,
                      const int* __restrict__ row_ptr, int* __restrict__ cursor,
                      int* __restrict__ csr_src, int* __restrict__ csr_dst,
                      int* __restrict__ csr_eid, int E, int N) {
    int e = blockIdx.x * blockDim.x + threadIdx.x;
    if (e >= E) return;
    int d = clampi(dst[e], N);
    int pos = row_ptr[d] + atomicAdd(&cursor[d], 1);
    if (pos < E) {
        csr_src[pos] = clampi(src[e], N);
        csr_dst[pos] = d;
        csr_eid[pos] = e;
    }
}

// ---------------- graph node counts — LDS histogram ----------------
#define MAXB 2048
__global__ void k_gse(const int* __restrict__ batch, int* __restrict__ gcnt, int N, int B) {
    __shared__ int s_cnt[MAXB];
    int t = threadIdx.x;
    int Bc = B < MAXB ? B : MAXB;
    for (int i = t; i < Bc; i += blockDim.x) s_cnt[i] = 0;
    __syncthreads();
    int n = blockIdx.x * blockDim.x + t;
    if (n < N) {
        int b = clampi(batch[n], B);
        if (b < MAXB) atomicAdd(&s_cnt[b], 1);
        else atomicAdd(&gcnt[b], 1);
    }
    __syncthreads();
    for (int i = t; i < Bc; i += blockDim.x)
        if (s_cnt[i] != 0) atomicAdd(&gcnt[i], s_cnt[i]);
}

// ---------------- ea_self[n,:] = mean of relu(edge_attr@eemb_W+b) over incoming ----------------
__global__ __launch_bounds__(256) void k_eaself(
    const float* __restrict__ edge_attr, const float* __restrict__ eW,
    const float* __restrict__ eB, const int* __restrict__ row_ptr,
    const int* __restrict__ csr_eid, float* __restrict__ ea_self, int N) {
    int wave = threadIdx.x >> 6, lane = threadIdx.x & 63;
    int n = blockIdx.x * 4 + wave;
    if (n >= N) return;
    float w0 = eW[0 * HD + lane], w1 = eW[1 * HD + lane];
    float w2 = eW[2 * HD + lane], w3 = eW[3 * HD + lane];
    float bb = eB[lane];
    int r0 = row_ptr[n], r1 = row_ptr[n + 1];
    float acc = 0.f;
    for (int j = r0; j < r1; j++) {
        int e = csr_eid[j];
        float a0 = edge_attr[e * 4 + 0], a1 = edge_attr[e * 4 + 1];
        float a2 = edge_attr[e * 4 + 2], a3 = edge_attr[e * 4 + 3];
        float v = fmaf(a0, w0, fmaf(a1, w1, fmaf(a2, w2, fmaf(a3, w3, bb))));
        acc += fmaxf(v, 0.f);
    }
    ea_self[n * HD + lane] = acc / fmaxf((float)(r1 - r0), 1.f);
}

// ---------------- per-layer: a_ed for E real edges + N self loops (edge-id order) ----
__global__ __launch_bounds__(256) void k_aed(
    const float* __restrict__ edge_attr, const float* __restrict__ eW,
    const float* __restrict__ eB, const float* __restrict__ We,
    const float* __restrict__ ae, const float* __restrict__ ea_self,
    float* __restrict__ a_ed, int E, int N) {
    __shared__ float s_wred[256];  // [h*64+d] = sum_c We[d,h*64+c] * ae[h,c]
    __shared__ float s_ew[256];    // [k*64+d]
    __shared__ float s_eb[64];
    int t = threadIdx.x;
    {
        int h = t >> 6, d = t & 63;
        float acc = 0.f;
        for (int c = 0; c < 64; c++)
            acc = fmaf(We[d * 256 + h * 64 + c], ae[h * 64 + c], acc);
        s_wred[t] = acc;
        s_ew[t] = eW[t];
        if (t < 64) s_eb[t] = eB[t];
    }
    __syncthreads();
    int item = blockIdx.x * blockDim.x + t;
    if (item < E) {
        float a0 = edge_attr[item * 4 + 0], a1 = edge_attr[item * 4 + 1];
        float a2 = edge_attr[item * 4 + 2], a3 = edge_attr[item * 4 + 3];
        float h0 = 0.f, h1 = 0.f, h2 = 0.f, h3 = 0.f;
        for (int d = 0; d < HD; d++) {
            float v = fmaf(a0, s_ew[d], fmaf(a1, s_ew[64 + d],
                      fmaf(a2, s_ew[128 + d], fmaf(a3, s_ew[192 + d], s_eb[d]))));
            v = fmaxf(v, 0.f);
            h0 = fmaf(v, s_wred[d], h0);
            h1 = fmaf(v, s_wred[64 + d], h1);
            h2 = fmaf(v, s_wred[128 + d], h2);
            h3 = fmaf(v, s_wred[192 + d], h3);
        }
        *(float4*)(a_ed + (size_t)item * 4) = make_float4(h0, h1, h2, h3);
    } else if (item < E + N) {
        int n = item - E;
        float h0 = 0.f, h1 = 0.f, h2 = 0.f, h3 = 0.f;
        for (int d = 0; d < HD; d++) {
            float v = ea_self[n * HD + d];
            h0 = fmaf(v, s_wred[d], h0);
            h1 = fmaf(v, s_wred[64 + d], h1);
            h2 = fmaf(v, s_wred[128 + d], h2);
            h3 = fmaf(v, s_wred[192 + d], h3);
        }
        *(float4*)(a_ed + (size_t)item * 4) = make_float4(h0, h1, h2, h3);
    }
}

// ---------------- per-layer: xp = h@W, 8 nodes per block ----------------
__global__ __launch_bounds__(256) void k_xp(
    const float* __restrict__ h, const float* __restrict__ W,
    const float* __restrict__ asrc, const float* __restrict__ adst,
    u16* __restrict__ xp, float* __restrict__ a_s, float* __restrict__ a_d, int N) {
    __shared__ float hs[8 * HD];
    int n0 = blockIdx.x * 8;
    int t = threadIdx.x;
    for (int i = t; i < 8 * HD; i += 256) {
        int nn = n0 + (i >> 6);
        hs[i] = (nn < N) ? h[(size_t)nn * HD + (i & 63)] : 0.f;
    }
    __syncthreads();
    int c = t;
    float acc[8];
    #pragma unroll
    for (int k = 0; k < 8; k++) acc[k] = 0.f;
    for (int d = 0; d < HD; d++) {
        float wv = W[d * 256 + c];
        #pragma unroll
        for (int k = 0; k < 8; k++) acc[k] = fmaf(hs[k * HD + d], wv, acc[k]);
    }
    float as_ = asrc[c], ad_ = adst[c];
    int hh = c >> 6, cc = c & 63;
    #pragma unroll
    for (int k = 0; k < 8; k++) {
        int nn = n0 + k;
        float ps = acc[k] * as_;
        float pd = acc[k] * ad_;
        #pragma unroll
        for (int o = 32; o > 0; o >>= 1) {
            ps += __shfl_xor(ps, o);
            pd += __shfl_xor(pd, o);
        }
        if (nn < N) {
            xp[(size_t)nn * 256 + c] = f2bf(acc[k]);
            if (cc == 0) { a_s[nn * 4 + hh] = ps; a_d[nn * 4 + hh] = pd; }
        }
    }
}

// ---------------- per-layer: attention weights in CSR order (coalesced writes) ----
// Random READS (L2-resident a_s/a_d/a_ed), coalesced float4 write of wcsr[j].
// R13's scattered-write + atomics variant regressed (WRITE_SIZE 5->51 MB); this
// keeps writes sequential. Self-loop weights at wcsr[E+n].
__global__ __launch_bounds__(256) void k_w(
    const int* __restrict__ csr_src, const int* __restrict__ csr_dst,
    const int* __restrict__ csr_eid, const float* __restrict__ a_s,
    const float* __restrict__ a_d, const float* __restrict__ a_ed,
    float* __restrict__ wcsr, int E, int N) {
    int j = blockIdx.x * blockDim.x + threadIdx.x;
    if (j < E) {
        int s = csr_src[j], d = csr_dst[j], e = csr_eid[j];
        float4 as4 = *(const float4*)(a_s + s * 4);
        float4 ad4 = *(const float4*)(a_d + d * 4);
        float4 ae4 = *(const float4*)(a_ed + (size_t)e * 4);
        float w0 = __expf(lrelu(as4.x + ad4.x + ae4.x));
        float w1 = __expf(lrelu(as4.y + ad4.y + ae4.y));
        float w2 = __expf(lrelu(as4.z + ad4.z + ae4.z));
        float w3 = __expf(lrelu(as4.w + ad4.w + ae4.w));
        *(float4*)(wcsr + (size_t)j * 4) = make_float4(w0, w1, w2, w3);
    } else if (j < E + N) {
        int n = j - E;
        float4 as4 = *(const float4*)(a_s + n * 4);
        float4 ad4 = *(const float4*)(a_d + n * 4);
        float4 ae4 = *(const float4*)(a_ed + (size_t)j * 4);
        float w0 = __expf(lrelu(as4.x + ad4.x + ae4.x));
        float w1 = __expf(lrelu(as4.y + ad4.y + ae4.y));
        float w2 = __expf(lrelu(as4.z + ad4.z + ae4.z));
        float w3 = __expf(lrelu(as4.w + ad4.w + ae4.w));
        *(float4*)(wcsr + (size_t)j * 4) = make_float4(w0, w1, w2, w3);
    }
}

// ---------------- per-layer GAT aggregate: sequential w stream + xp gather ----
// Loop body: sequential csr_src[j]/wcsr[j], in-register den sum, one random
// bf16 row gather, 5 FMA. Gathers independent across iterations.
__global__ __launch_bounds__(256) void k_gat(
    const u16* __restrict__ xp, const float* __restrict__ wcsr,
    const int* __restrict__ row_ptr, const int* __restrict__ csr_src,
    const float* __restrict__ convb, float* __restrict__ h_out, int N, int E) {
    int wave = threadIdx.x >> 6, lane = threadIdx.x & 63;
    int n = blockIdx.x * 4 + wave;
    if (n >= N) return;
    int r0 = row_ptr[n], r1 = row_ptr[n + 1];
    int hl = lane >> 4;
    float wself = wcsr[(size_t)(E + n) * 4 + hl];
    float den = wself;
    ushort4 xv4 = *(const ushort4*)(xp + (size_t)n * 256 + lane * 4);
    float acc0 = wself * bf2f(xv4.x), acc1 = wself * bf2f(xv4.y);
    float acc2 = wself * bf2f(xv4.z), acc3 = wself * bf2f(xv4.w);
    for (int j = r0; j < r1; j++) {
        int s = csr_src[j];
        float w = wcsr[(size_t)j * 4 + hl];
        den += w;
        ushort4 x4 = *(const ushort4*)(xp + (size_t)s * 256 + lane * 4);
        acc0 = fmaf(w, bf2f(x4.x), acc0);
        acc1 = fmaf(w, bf2f(x4.y), acc1);
        acc2 = fmaf(w, bf2f(x4.z), acc2);
        acc3 = fmaf(w, bf2f(x4.w), acc3);
    }
    float invd = 1.f / den;
    acc0 *= invd; acc1 *= invd; acc2 *= invd; acc3 *= invd;
    // mean over heads
    acc0 += __shfl_xor(acc0, 16); acc0 += __shfl_xor(acc0, 32);
    acc1 += __shfl_xor(acc1, 16); acc1 += __shfl_xor(acc1, 32);
    acc2 += __shfl_xor(acc2, 16); acc2 += __shfl_xor(acc2, 32);
    acc3 += __shfl_xor(acc3, 16); acc3 += __shfl_xor(acc3, 32);
    if (lane < 16) {
        int c = lane * 4;
        h_out[(size_t)n * HD + c + 0] = fmaxf(0.25f * acc0 + convb[c + 0], 0.f);
        h_out[(size_t)n * HD + c + 1] = fmaxf(0.25f * acc1 + convb[c + 1], 0.f);
        h_out[(size_t)n * HD + c + 2] = fmaxf(0.25f * acc2 + convb[c + 2], 0.f);
        h_out[(size_t)n * HD + c + 3] = fmaxf(0.25f * acc3 + convb[c + 3], 0.f);
    }
}

// ---------------- global pool, node-parallel with atomics ----------------
__global__ void k_pool(const float* __restrict__ h, const int* __restrict__ batch,
                       float* __restrict__ pooled, int N, int B) {
    int i = blockIdx.x * blockDim.x + threadIdx.x;
    if (i >= N * HD) return;
    int n = i >> 6, c = i & 63;
    int b = clampi(batch[n], B);
    atomicAdd(&pooled[b * HD + c], h[i]);
}

// ---------------- final MLP (fp32 out; divides pooled sum by count) ----------------
__global__ void k_mlp(const float* __restrict__ u, const float* __restrict__ gW,
                      const float* __restrict__ gb, const float* __restrict__ pooled,
                      const int* __restrict__ gcnt, const float* __restrict__ f1W,
                      const float* __restrict__ f1b, const float* __restrict__ f2W,
                      const float* __restrict__ f2b, float* __restrict__ out, int B) {
    __shared__ float z[2 * HD];
    __shared__ float z1s[HD];
    int b = blockIdx.x, t = threadIdx.x;  // 64 threads
    float acc = gb[t];
    for (int k = 0; k < 10; k++) acc = fmaf(u[b * 10 + k], gW[k * HD + t], acc);
    z[HD + t] = fmaxf(acc, 0.f);
    float invc = 1.f / fmaxf((float)gcnt[b], 1.f);
    z[t] = pooled[b * HD + t] * invc;
    __syncthreads();
    float a1 = f1b[t];
    for (int k = 0; k < 2 * HD; k++) a1 = fmaf(z[k], f1W[k * HD + t], a1);
    z1s[t] = fmaxf(a1, 0.f);
    __syncthreads();
    if (t < 2) {
        float o = f2b[t];
        for (int k = 0; k < HD; k++) o = fmaf(z1s[k], f2W[k * 2 + t], o);
        out[b * 2 + t] = o;
    }
}

extern "C" void kernel_launch(void* const* d_in, const int* in_sizes, int n_in,
                              void* d_out, int out_size, void* d_ws, size_t ws_size,
                              hipStream_t stream) {
    const float* x         = (const float*)d_in[0];
    const int*   ei        = (const int*)d_in[1];
    const float* edge_attr = (const float*)d_in[2];
    const float* u         = (const float*)d_in[3];
    const int*   batch     = (const int*)d_in[4];
    const float* node_W    = (const float*)d_in[5];
    const float* node_b    = (const float*)d_in[6];
    const float* eemb_W    = (const float*)d_in[7];
    const float* eemb_b    = (const float*)d_in[8];
    const float* lin_W     = (const float*)d_in[9];
    const float* att_src   = (const float*)d_in[10];
    const float* att_dst   = (const float*)d_in[11];
    const float* lin_eW    = (const float*)d_in[12];
    const float* att_e     = (const float*)d_in[13];
    const float* conv_b    = (const float*)d_in[14];
    const float* gW        = (const float*)d_in[15];
    const float* gb        = (const float*)d_in[16];
    const float* f1W       = (const float*)d_in[17];
    const float* f1b       = (const float*)d_in[18];
    const float* f2W       = (const float*)d_in[19];
    const float* f2b       = (const float*)d_in[20];

    const int N = in_sizes[0] / 3;
    const int E = in_sizes[2] / 4;
    const int B = in_sizes[3] / 10;
    const int* src = ei;
    const int* dst = ei + E;
    const int NB = (N + 255) / 256;   // scan blocks

    // workspace carve (fp32 then bf16 then ints)
    float* wsf = (float*)d_ws;
    float* h       = wsf;              wsf += (size_t)N * HD;
    float* a_s     = wsf;              wsf += (size_t)N * 4;
    float* a_d     = wsf;              wsf += (size_t)N * 4;
    float* ea_self = wsf;              wsf += (size_t)N * HD;
    float* a_ed    = wsf;              wsf += (size_t)(E + N) * 4;
    float* wcsr    = wsf;              wsf += (size_t)(E + N) * 4;
    float* pooled  = wsf;              wsf += (size_t)B * HD;
    u16* xp = (u16*)wsf;               wsf += (size_t)N * 128;   // N*256 bf16
    int* wsi = (int*)wsf;
    int* deg     = wsi;                wsi += N;
    int* row_ptr = wsi;                wsi += N + 1;
    int* cursor  = wsi;                wsi += N;
    int* tmp     = wsi;                wsi += N;
    int* bsum    = wsi;                wsi += NB + 1;
    int* boff    = wsi;                wsi += NB + 1;
    int* csr_src = wsi;                wsi += E;
    int* csr_dst = wsi;                wsi += E;
    int* csr_eid = wsi;                wsi += E;
    int* gcnt    = wsi;                wsi += B;

    k_init<<<NB, 256, 0, stream>>>(deg, cursor, gcnt, pooled, N, B);
    k_node_emb<<<(N * HD + 255) / 256, 256, 0, stream>>>(x, node_W, node_b, h, N);
    k_deg<<<(E + 255) / 256, 256, 0, stream>>>(dst, deg, E, N);
    k_scan1<<<NB, 256, 0, stream>>>(deg, tmp, bsum, N);
    k_scan2<<<1, 1024, 0, stream>>>(bsum, boff, NB);
    k_scan3<<<NB, 256, 0, stream>>>(tmp, boff, row_ptr, N);
    k_csr<<<(E + 255) / 256, 256, 0, stream>>>(src, dst, row_ptr, cursor,
                                               csr_src, csr_dst, csr_eid, E, N);
    k_gse<<<NB, 256, 0, stream>>>(batch, gcnt, N, B);
    k_eaself<<<(N + 3) / 4, 256, 0, stream>>>(edge_attr, eemb_W, eemb_b, row_ptr, csr_eid,
                                              ea_self, N);
    for (int i = 0; i < 3; i++) {
        k_xp<<<(N + 7) / 8, 256, 0, stream>>>(h, lin_W + (size_t)i * HD * 256,
                                              att_src + (size_t)i * 256,
                                              att_dst + (size_t)i * 256,
                                              xp, a_s, a_d, N);
        k_aed<<<(E + N + 255) / 256, 256, 0, stream>>>(
            edge_attr, eemb_W, eemb_b, lin_eW + (size_t)i * HD * 256,
            att_e + (size_t)i * 256, ea_self, a_ed, E, N);
        k_w<<<(E + N + 255) / 256, 256, 0, stream>>>(csr_src, csr_dst, csr_eid,
                                                     a_s, a_d, a_ed, wcsr, E, N);
        k_gat<<<(N + 3) / 4, 256, 0, stream>>>(xp, wcsr, row_ptr, csr_src,
                                               conv_b + (size_t)i * HD, h, N, E);
    }
    k_pool<<<(N * HD + 255) / 256, 256, 0, stream>>>(h, batch, pooled, N, B);
    k_mlp<<<B, 64, 0, stream>>>(u, gW, gb, pooled, gcnt, f1W, f1b, f2W, f2b,
                                (float*)d_out, B);
}

// Round 15
// 457.699 us; speedup vs baseline: 1.5549x; 1.1426x over previous
//
#include <hip/hip_runtime.h>
#include <hip/hip_bf16.h>

#define HD 64

typedef unsigned short u16;

__device__ __forceinline__ float lrelu(float x) { return x > 0.f ? x : 0.2f * x; }
__device__ __forceinline__ int clampi(int v, int maxv) {
    return v < 0 ? 0 : (v >= maxv ? maxv - 1 : v);
}
__device__ __forceinline__ float bf2f(u16 u) {
    return __uint_as_float(((unsigned int)u) << 16);
}
// round-to-nearest-even fp32 -> bf16 (bit-level; inputs are finite)
__device__ __forceinline__ u16 f2bf(float f) {
    unsigned int u = __float_as_uint(f);
    unsigned int lsb = (u >> 16) & 1u;
    u += 0x7fffu + lsb;
    return (u16)(u >> 16);
}

// ---------------- init: zero deg/cursor/pooled/gcnt ----------------
__global__ void k_init(int* deg, int* cursor, int* gcnt, float* pooled, int N, int B) {
    int i = blockIdx.x * blockDim.x + threadIdx.x;
    if (i < N) { deg[i] = 0; cursor[i] = 0; }
    if (i < B) gcnt[i] = 0;
    if (i < B * HD) pooled[i] = 0.f;
}

// ---------------- h = relu(x @ node_W + node_b),  x:[N,3] W:[3,64] ----------------
__global__ void k_node_emb(const float* __restrict__ x, const float* __restrict__ W,
                           const float* __restrict__ b, float* __restrict__ h, int N) {
    int i = blockIdx.x * blockDim.x + threadIdx.x;
    if (i >= N * HD) return;
    int n = i >> 6, c = i & 63;
    float acc = b[c];
    acc = fmaf(x[n * 3 + 0], W[0 * HD + c], acc);
    acc = fmaf(x[n * 3 + 1], W[1 * HD + c], acc);
    acc = fmaf(x[n * 3 + 2], W[2 * HD + c], acc);
    h[i] = fmaxf(acc, 0.f);
}

// ---------------- degree histogram over dst ----------------
__global__ void k_deg(const int* __restrict__ dst, int* __restrict__ deg, int E, int N) {
    int e = blockIdx.x * blockDim.x + threadIdx.x;
    if (e < E) atomicAdd(&deg[clampi(dst[e], N)], 1);
}

// ---------------- hierarchical scan ----------------
__global__ void k_scan1(const int* __restrict__ deg, int* __restrict__ tmp,
                        int* __restrict__ bsum, int N) {
    __shared__ int s[256];
    int tid = threadIdx.x;
    int i = blockIdx.x * 256 + tid;
    int v = (i < N) ? deg[i] : 0;
    s[tid] = v;
    __syncthreads();
    for (int off = 1; off < 256; off <<= 1) {
        int t = (tid >= off) ? s[tid - off] : 0;
        __syncthreads();
        s[tid] += t;
        __syncthreads();
    }
    if (i < N) tmp[i] = s[tid];
    if (tid == 255) bsum[blockIdx.x] = s[255];
}
__global__ void k_scan2(const int* __restrict__ bsum, int* __restrict__ boff, int nb) {
    __shared__ int s[1024];
    int tid = threadIdx.x;
    int v = (tid < nb) ? bsum[tid] : 0;
    s[tid] = v;
    __syncthreads();
    for (int off = 1; off < 1024; off <<= 1) {
        int t = (tid >= off) ? s[tid - off] : 0;
        __syncthreads();
        s[tid] += t;
        __syncthreads();
    }
    if (tid < nb) boff[tid] = s[tid] - v;   // exclusive
}
__global__ void k_scan3(const int* __restrict__ tmp, const int* __restrict__ boff,
                        int* __restrict__ row_ptr, int N) {
    int i = blockIdx.x * blockDim.x + threadIdx.x;
    if (i == 0) row_ptr[0] = 0;
    if (i < N) row_ptr[i + 1] = tmp[i] + boff[i >> 8];
}

// ---------------- CSR scatter; stores src, dst, eid per csr slot ----------------
__global__ void k_csr(const int* __restrict__ src, const int* __restrict__ dst,
                      const int* __restrict__ row_ptr, int* __restrict__ cursor,
                      int* __restrict__ csr_src, int* __restrict__ csr_dst,
                      int* __restrict__ csr_eid, int E, int N) {
    int e = blockIdx.x * blockDim.x + threadIdx.x;
    if (e >= E) return;
    int d = clampi(dst[e], N);
    int pos = row_ptr[d] + atomicAdd(&cursor[d], 1);
    if (pos < E) {
        csr_src[pos] = clampi(src[e], N);
        csr_dst[pos] = d;
        csr_eid[pos] = e;
    }
}

// ---------------- graph node counts — LDS histogram ----------------
#define MAXB 2048
__global__ void k_gse(const int* __restrict__ batch, int* __restrict__ gcnt, int N, int B) {
    __shared__ int s_cnt[MAXB];
    int t = threadIdx.x;
    int Bc = B < MAXB ? B : MAXB;
    for (int i = t; i < Bc; i += blockDim.x) s_cnt[i] = 0;
    __syncthreads();
    int n = blockIdx.x * blockDim.x + t;
    if (n < N) {
        int b = clampi(batch[n], B);
        if (b < MAXB) atomicAdd(&s_cnt[b], 1);
        else atomicAdd(&gcnt[b], 1);
    }
    __syncthreads();
    for (int i = t; i < Bc; i += blockDim.x)
        if (s_cnt[i] != 0) atomicAdd(&gcnt[i], s_cnt[i]);
}

// ---------------- ea_self[n,:] = mean of relu(edge_attr@eemb_W+b) over incoming ----------------
__global__ __launch_bounds__(256) void k_eaself(
    const float* __restrict__ edge_attr, const float* __restrict__ eW,
    const float* __restrict__ eB, const int* __restrict__ row_ptr,
    const int* __restrict__ csr_eid, float* __restrict__ ea_self, int N) {
    int wave = threadIdx.x >> 6, lane = threadIdx.x & 63;
    int n = blockIdx.x * 4 + wave;
    if (n >= N) return;
    float w0 = eW[0 * HD + lane], w1 = eW[1 * HD + lane];
    float w2 = eW[2 * HD + lane], w3 = eW[3 * HD + lane];
    float bb = eB[lane];
    int r0 = row_ptr[n], r1 = row_ptr[n + 1];
    float acc = 0.f;
    for (int j = r0; j < r1; j++) {
        int e = csr_eid[j];
        float a0 = edge_attr[e * 4 + 0], a1 = edge_attr[e * 4 + 1];
        float a2 = edge_attr[e * 4 + 2], a3 = edge_attr[e * 4 + 3];
        float v = fmaf(a0, w0, fmaf(a1, w1, fmaf(a2, w2, fmaf(a3, w3, bb))));
        acc += fmaxf(v, 0.f);
    }
    ea_self[n * HD + lane] = acc / fmaxf((float)(r1 - r0), 1.f);
}

// ---------------- per-layer: xp = h@W, 8 nodes per block ----------------
__global__ __launch_bounds__(256) void k_xp(
    const float* __restrict__ h, const float* __restrict__ W,
    const float* __restrict__ asrc, const float* __restrict__ adst,
    u16* __restrict__ xp, float* __restrict__ a_s, float* __restrict__ a_d, int N) {
    __shared__ float hs[8 * HD];
    int n0 = blockIdx.x * 8;
    int t = threadIdx.x;
    for (int i = t; i < 8 * HD; i += 256) {
        int nn = n0 + (i >> 6);
        hs[i] = (nn < N) ? h[(size_t)nn * HD + (i & 63)] : 0.f;
    }
    __syncthreads();
    int c = t;
    float acc[8];
    #pragma unroll
    for (int k = 0; k < 8; k++) acc[k] = 0.f;
    for (int d = 0; d < HD; d++) {
        float wv = W[d * 256 + c];
        #pragma unroll
        for (int k = 0; k < 8; k++) acc[k] = fmaf(hs[k * HD + d], wv, acc[k]);
    }
    float as_ = asrc[c], ad_ = adst[c];
    int hh = c >> 6, cc = c & 63;
    #pragma unroll
    for (int k = 0; k < 8; k++) {
        int nn = n0 + k;
        float ps = acc[k] * as_;
        float pd = acc[k] * ad_;
        #pragma unroll
        for (int o = 32; o > 0; o >>= 1) {
            ps += __shfl_xor(ps, o);
            pd += __shfl_xor(pd, o);
        }
        if (nn < N) {
            xp[(size_t)nn * 256 + c] = f2bf(acc[k]);
            if (cc == 0) { a_s[nn * 4 + hh] = ps; a_d[nn * 4 + hh] = pd; }
        }
    }
}

// ---------------- per-layer: attention weights in CSR order, a_ed fused inline ----
// Per csr slot j: random 16B edge_attr read (L2-resident), 64-iter dot with LDS
// weights, w = exp(lrelu(a_s[src]+a_d[dst]+a_ed)). Coalesced float4 wcsr write.
// Self loops at slots E..E+N use ea_self. (Merges R14's k_aed+k_w; removes the
// a_ed array round-trip.)
__global__ __launch_bounds__(256) void k_w(
    const float* __restrict__ edge_attr, const float* __restrict__ eW,
    const float* __restrict__ eB, const float* __restrict__ We,
    const float* __restrict__ ae, const float* __restrict__ ea_self,
    const int* __restrict__ csr_src, const int* __restrict__ csr_dst,
    const int* __restrict__ csr_eid, const float* __restrict__ a_s,
    const float* __restrict__ a_d, float* __restrict__ wcsr, int E, int N) {
    __shared__ float s_wred[256];  // [h*64+d] = sum_c We[d,h*64+c] * ae[h,c]
    __shared__ float s_ew[256];    // [k*64+d]
    __shared__ float s_eb[64];
    int t = threadIdx.x;
    {
        int h = t >> 6, d = t & 63;
        float acc = 0.f;
        for (int c = 0; c < 64; c++)
            acc = fmaf(We[d * 256 + h * 64 + c], ae[h * 64 + c], acc);
        s_wred[t] = acc;
        s_ew[t] = eW[t];
        if (t < 64) s_eb[t] = eB[t];
    }
    __syncthreads();
    int j = blockIdx.x * blockDim.x + t;
    float h0 = 0.f, h1 = 0.f, h2 = 0.f, h3 = 0.f;
    int s, d;
    if (j < E) {
        int e = csr_eid[j];
        float4 a = *(const float4*)(edge_attr + (size_t)e * 4);
        for (int k = 0; k < HD; k++) {
            float v = fmaf(a.x, s_ew[k], fmaf(a.y, s_ew[64 + k],
                      fmaf(a.z, s_ew[128 + k], fmaf(a.w, s_ew[192 + k], s_eb[k]))));
            v = fmaxf(v, 0.f);
            h0 = fmaf(v, s_wred[k], h0);
            h1 = fmaf(v, s_wred[64 + k], h1);
            h2 = fmaf(v, s_wred[128 + k], h2);
            h3 = fmaf(v, s_wred[192 + k], h3);
        }
        s = csr_src[j];
        d = csr_dst[j];
    } else if (j < E + N) {
        int n = j - E;
        for (int k = 0; k < HD; k++) {
            float v = ea_self[n * HD + k];
            h0 = fmaf(v, s_wred[k], h0);
            h1 = fmaf(v, s_wred[64 + k], h1);
            h2 = fmaf(v, s_wred[128 + k], h2);
            h3 = fmaf(v, s_wred[192 + k], h3);
        }
        s = n;
        d = n;
    } else {
        return;
    }
    float4 as4 = *(const float4*)(a_s + s * 4);
    float4 ad4 = *(const float4*)(a_d + d * 4);
    float w0 = __expf(lrelu(as4.x + ad4.x + h0));
    float w1 = __expf(lrelu(as4.y + ad4.y + h1));
    float w2 = __expf(lrelu(as4.z + ad4.z + h2));
    float w3 = __expf(lrelu(as4.w + ad4.w + h3));
    *(float4*)(wcsr + (size_t)j * 4) = make_float4(w0, w1, w2, w3);
}

// ---------------- per-layer GAT aggregate: edge-parallel within wave ----------------
// Wave = 1 node; 4 subgroups x 16 lanes; subgroup g handles edges j%4==g, so 4
// edges and 16 row-loads are in flight (R14 version had 1 -> latency-bound at
// 43 us, VALU 20%). Lane owns within-head channels 4p..4p+3 for ALL 4 heads
// (16 accumulators). Head-mean is in-lane; cross-subgroup combine = 16 shfls.
__global__ __launch_bounds__(256) void k_gat(
    const u16* __restrict__ xp, const float* __restrict__ wcsr,
    const int* __restrict__ row_ptr, const int* __restrict__ csr_src,
    const float* __restrict__ convb, float* __restrict__ h_out, int N, int E) {
    int wave = threadIdx.x >> 6, lane = threadIdx.x & 63;
    int n = blockIdx.x * 4 + wave;
    if (n >= N) return;
    int g = lane >> 4, p = lane & 15;
    int r0 = row_ptr[n], r1 = row_ptr[n + 1];
    float a00 = 0.f, a01 = 0.f, a02 = 0.f, a03 = 0.f;
    float a10 = 0.f, a11 = 0.f, a12 = 0.f, a13 = 0.f;
    float a20 = 0.f, a21 = 0.f, a22 = 0.f, a23 = 0.f;
    float a30 = 0.f, a31 = 0.f, a32 = 0.f, a33 = 0.f;
    float d0 = 0.f, d1 = 0.f, d2 = 0.f, d3 = 0.f;
    // self loop: subgroup 0 only
    if (g == 0) {
        float4 w = *(const float4*)(wcsr + (size_t)(E + n) * 4);
        const u16* row = xp + (size_t)n * 256 + p * 4;
        ushort4 v0 = *(const ushort4*)(row);
        ushort4 v1 = *(const ushort4*)(row + 64);
        ushort4 v2 = *(const ushort4*)(row + 128);
        ushort4 v3 = *(const ushort4*)(row + 192);
        d0 += w.x; d1 += w.y; d2 += w.z; d3 += w.w;
        a00 = fmaf(w.x, bf2f(v0.x), a00); a01 = fmaf(w.x, bf2f(v0.y), a01);
        a02 = fmaf(w.x, bf2f(v0.z), a02); a03 = fmaf(w.x, bf2f(v0.w), a03);
        a10 = fmaf(w.y, bf2f(v1.x), a10); a11 = fmaf(w.y, bf2f(v1.y), a11);
        a12 = fmaf(w.y, bf2f(v1.z), a12); a13 = fmaf(w.y, bf2f(v1.w), a13);
        a20 = fmaf(w.z, bf2f(v2.x), a20); a21 = fmaf(w.z, bf2f(v2.y), a21);
        a22 = fmaf(w.z, bf2f(v2.z), a22); a23 = fmaf(w.z, bf2f(v2.w), a23);
        a30 = fmaf(w.w, bf2f(v3.x), a30); a31 = fmaf(w.w, bf2f(v3.y), a31);
        a32 = fmaf(w.w, bf2f(v3.z), a32); a33 = fmaf(w.w, bf2f(v3.w), a33);
    }
    for (int j = r0 + g; j < r1; j += 4) {
        float4 w = *(const float4*)(wcsr + (size_t)j * 4);
        const u16* row = xp + (size_t)csr_src[j] * 256 + p * 4;
        ushort4 v0 = *(const ushort4*)(row);
        ushort4 v1 = *(const ushort4*)(row + 64);
        ushort4 v2 = *(const ushort4*)(row + 128);
        ushort4 v3 = *(const ushort4*)(row + 192);
        d0 += w.x; d1 += w.y; d2 += w.z; d3 += w.w;
        a00 = fmaf(w.x, bf2f(v0.x), a00); a01 = fmaf(w.x, bf2f(v0.y), a01);
        a02 = fmaf(w.x, bf2f(v0.z), a02); a03 = fmaf(w.x, bf2f(v0.w), a03);
        a10 = fmaf(w.y, bf2f(v1.x), a10); a11 = fmaf(w.y, bf2f(v1.y), a11);
        a12 = fmaf(w.y, bf2f(v1.z), a12); a13 = fmaf(w.y, bf2f(v1.w), a13);
        a20 = fmaf(w.z, bf2f(v2.x), a20); a21 = fmaf(w.z, bf2f(v2.y), a21);
        a22 = fmaf(w.z, bf2f(v2.z), a22); a23 = fmaf(w.z, bf2f(v2.w), a23);
        a30 = fmaf(w.w, bf2f(v3.x), a30); a31 = fmaf(w.w, bf2f(v3.y), a31);
        a32 = fmaf(w.w, bf2f(v3.z), a32); a33 = fmaf(w.w, bf2f(v3.w), a33);
    }
    // global denominators (sum over subgroups)
    d0 += __shfl_xor(d0, 16); d0 += __shfl_xor(d0, 32);
    d1 += __shfl_xor(d1, 16); d1 += __shfl_xor(d1, 32);
    d2 += __shfl_xor(d2, 16); d2 += __shfl_xor(d2, 32);
    d3 += __shfl_xor(d3, 16); d3 += __shfl_xor(d3, 32);
    float i0 = 1.f / d0, i1 = 1.f / d1, i2 = 1.f / d2, i3 = 1.f / d3;
    // in-lane head mean of this subgroup's partial, then cross-subgroup sum
    float m0 = a00 * i0 + a10 * i1 + a20 * i2 + a30 * i3;
    float m1 = a01 * i0 + a11 * i1 + a21 * i2 + a31 * i3;
    float m2 = a02 * i0 + a12 * i1 + a22 * i2 + a32 * i3;
    float m3 = a03 * i0 + a13 * i1 + a23 * i2 + a33 * i3;
    m0 += __shfl_xor(m0, 16); m0 += __shfl_xor(m0, 32);
    m1 += __shfl_xor(m1, 16); m1 += __shfl_xor(m1, 32);
    m2 += __shfl_xor(m2, 16); m2 += __shfl_xor(m2, 32);
    m3 += __shfl_xor(m3, 16); m3 += __shfl_xor(m3, 32);
    if (lane < 16) {
        int c = p * 4;
        h_out[(size_t)n * HD + c + 0] = fmaxf(0.25f * m0 + convb[c + 0], 0.f);
        h_out[(size_t)n * HD + c + 1] = fmaxf(0.25f * m1 + convb[c + 1], 0.f);
        h_out[(size_t)n * HD + c + 2] = fmaxf(0.25f * m2 + convb[c + 2], 0.f);
        h_out[(size_t)n * HD + c + 3] = fmaxf(0.25f * m3 + convb[c + 3], 0.f);
    }
}

// ---------------- global pool, node-parallel with atomics ----------------
__global__ void k_pool(const float* __restrict__ h, const int* __restrict__ batch,
                       float* __restrict__ pooled, int N, int B) {
    int i = blockIdx.x * blockDim.x + threadIdx.x;
    if (i >= N * HD) return;
    int n = i >> 6, c = i & 63;
    int b = clampi(batch[n], B);
    atomicAdd(&pooled[b * HD + c], h[i]);
}

// ---------------- final MLP (fp32 out; divides pooled sum by count) ----------------
__global__ void k_mlp(const float* __restrict__ u, const float* __restrict__ gW,
                      const float* __restrict__ gb, const float* __restrict__ pooled,
                      const int* __restrict__ gcnt, const float* __restrict__ f1W,
                      const float* __restrict__ f1b, const float* __restrict__ f2W,
                      const float* __restrict__ f2b, float* __restrict__ out, int B) {
    __shared__ float z[2 * HD];
    __shared__ float z1s[HD];
    int b = blockIdx.x, t = threadIdx.x;  // 64 threads
    float acc = gb[t];
    for (int k = 0; k < 10; k++) acc = fmaf(u[b * 10 + k], gW[k * HD + t], acc);
    z[HD + t] = fmaxf(acc, 0.f);
    float invc = 1.f / fmaxf((float)gcnt[b], 1.f);
    z[t] = pooled[b * HD + t] * invc;
    __syncthreads();
    float a1 = f1b[t];
    for (int k = 0; k < 2 * HD; k++) a1 = fmaf(z[k], f1W[k * HD + t], a1);
    z1s[t] = fmaxf(a1, 0.f);
    __syncthreads();
    if (t < 2) {
        float o = f2b[t];
        for (int k = 0; k < HD; k++) o = fmaf(z1s[k], f2W[k * 2 + t], o);
        out[b * 2 + t] = o;
    }
}

extern "C" void kernel_launch(void* const* d_in, const int* in_sizes, int n_in,
                              void* d_out, int out_size, void* d_ws, size_t ws_size,
                              hipStream_t stream) {
    const float* x         = (const float*)d_in[0];
    const int*   ei        = (const int*)d_in[1];
    const float* edge_attr = (const float*)d_in[2];
    const float* u         = (const float*)d_in[3];
    const int*   batch     = (const int*)d_in[4];
    const float* node_W    = (const float*)d_in[5];
    const float* node_b    = (const float*)d_in[6];
    const float* eemb_W    = (const float*)d_in[7];
    const float* eemb_b    = (const float*)d_in[8];
    const float* lin_W     = (const float*)d_in[9];
    const float* att_src   = (const float*)d_in[10];
    const float* att_dst   = (const float*)d_in[11];
    const float* lin_eW    = (const float*)d_in[12];
    const float* att_e     = (const float*)d_in[13];
    const float* conv_b    = (const float*)d_in[14];
    const float* gW        = (const float*)d_in[15];
    const float* gb        = (const float*)d_in[16];
    const float* f1W       = (const float*)d_in[17];
    const float* f1b       = (const float*)d_in[18];
    const float* f2W       = (const float*)d_in[19];
    const float* f2b       = (const float*)d_in[20];

    const int N = in_sizes[0] / 3;
    const int E = in_sizes[2] / 4;
    const int B = in_sizes[3] / 10;
    const int* src = ei;
    const int* dst = ei + E;
    const int NB = (N + 255) / 256;   // scan blocks

    // workspace carve (fp32 then bf16 then ints)
    float* wsf = (float*)d_ws;
    float* h       = wsf;              wsf += (size_t)N * HD;
    float* a_s     = wsf;              wsf += (size_t)N * 4;
    float* a_d     = wsf;              wsf += (size_t)N * 4;
    float* ea_self = wsf;              wsf += (size_t)N * HD;
    float* wcsr    = wsf;              wsf += (size_t)(E + N) * 4;
    float* pooled  = wsf;              wsf += (size_t)B * HD;
    u16* xp = (u16*)wsf;               wsf += (size_t)N * 128;   // N*256 bf16
    int* wsi = (int*)wsf;
    int* deg     = wsi;                wsi += N;
    int* row_ptr = wsi;                wsi += N + 1;
    int* cursor  = wsi;                wsi += N;
    int* tmp     = wsi;                wsi += N;
    int* bsum    = wsi;                wsi += NB + 1;
    int* boff    = wsi;                wsi += NB + 1;
    int* csr_src = wsi;                wsi += E;
    int* csr_dst = wsi;                wsi += E;
    int* csr_eid = wsi;                wsi += E;
    int* gcnt    = wsi;                wsi += B;

    k_init<<<NB, 256, 0, stream>>>(deg, cursor, gcnt, pooled, N, B);
    k_node_emb<<<(N * HD + 255) / 256, 256, 0, stream>>>(x, node_W, node_b, h, N);
    k_deg<<<(E + 255) / 256, 256, 0, stream>>>(dst, deg, E, N);
    k_scan1<<<NB, 256, 0, stream>>>(deg, tmp, bsum, N);
    k_scan2<<<1, 1024, 0, stream>>>(bsum, boff, NB);
    k_scan3<<<NB, 256, 0, stream>>>(tmp, boff, row_ptr, N);
    k_csr<<<(E + 255) / 256, 256, 0, stream>>>(src, dst, row_ptr, cursor,
                                               csr_src, csr_dst, csr_eid, E, N);
    k_gse<<<NB, 256, 0, stream>>>(batch, gcnt, N, B);
    k_eaself<<<(N + 3) / 4, 256, 0, stream>>>(edge_attr, eemb_W, eemb_b, row_ptr, csr_eid,
                                              ea_self, N);
    for (int i = 0; i < 3; i++) {
        k_xp<<<(N + 7) / 8, 256, 0, stream>>>(h, lin_W + (size_t)i * HD * 256,
                                              att_src + (size_t)i * 256,
                                              att_dst + (size_t)i * 256,
                                              xp, a_s, a_d, N);
        k_w<<<(E + N + 255) / 256, 256, 0, stream>>>(
            edge_attr, eemb_W, eemb_b, lin_eW + (size_t)i * HD * 256,
            att_e + (size_t)i * 256, ea_self, csr_src, csr_dst, csr_eid,
            a_s, a_d, wcsr, E, N);
        k_gat<<<(N + 3) / 4, 256, 0, stream>>>(xp, wcsr, row_ptr, csr_src,
                                               conv_b + (size_t)i * HD, h, N, E);
    }
    k_pool<<<(N * HD + 255) / 256, 256, 0, stream>>>(h, batch, pooled, N, B);
    k_mlp<<<B, 64, 0, stream>>>(u, gW, gb, pooled, gcnt, f1W, f1b, f2W, f2b,
                                (float*)d_out, B);
}

// Round 16
// 422.445 us; speedup vs baseline: 1.6847x; 1.0835x over previous
//
#include <hip/hip_runtime.h>
#include <hip/hip_bf16.h>

#define HD 64

typedef unsigned short u16;

__device__ __forceinline__ float lrelu(float x) { return x > 0.f ? x : 0.2f * x; }
__device__ __forceinline__ int clampi(int v, int maxv) {
    return v < 0 ? 0 : (v >= maxv ? maxv - 1 : v);
}
__device__ __forceinline__ float bf2f(u16 u) {
    return __uint_as_float(((unsigned int)u) << 16);
}
// round-to-nearest-even fp32 -> bf16 (bit-level; inputs are finite)
__device__ __forceinline__ u16 f2bf(float f) {
    unsigned int u = __float_as_uint(f);
    unsigned int lsb = (u >> 16) & 1u;
    u += 0x7fffu + lsb;
    return (u16)(u >> 16);
}

// ---------------- init: zero deg/cursor/pooled/gcnt ----------------
__global__ void k_init(int* deg, int* cursor, int* gcnt, float* pooled, int N, int B) {
    int i = blockIdx.x * blockDim.x + threadIdx.x;
    if (i < N) { deg[i] = 0; cursor[i] = 0; }
    if (i < B) gcnt[i] = 0;
    if (i < B * HD) pooled[i] = 0.f;
}

// ---------------- h = relu(x @ node_W + node_b),  x:[N,3] W:[3,64] ----------------
__global__ void k_node_emb(const float* __restrict__ x, const float* __restrict__ W,
                           const float* __restrict__ b, float* __restrict__ h, int N) {
    int i = blockIdx.x * blockDim.x + threadIdx.x;
    if (i >= N * HD) return;
    int n = i >> 6, c = i & 63;
    float acc = b[c];
    acc = fmaf(x[n * 3 + 0], W[0 * HD + c], acc);
    acc = fmaf(x[n * 3 + 1], W[1 * HD + c], acc);
    acc = fmaf(x[n * 3 + 2], W[2 * HD + c], acc);
    h[i] = fmaxf(acc, 0.f);
}

// ---------------- degree histogram over dst ----------------
__global__ void k_deg(const int* __restrict__ dst, int* __restrict__ deg, int E, int N) {
    int e = blockIdx.x * blockDim.x + threadIdx.x;
    if (e < E) atomicAdd(&deg[clampi(dst[e], N)], 1);
}

// ---------------- hierarchical scan ----------------
__global__ void k_scan1(const int* __restrict__ deg, int* __restrict__ tmp,
                        int* __restrict__ bsum, int N) {
    __shared__ int s[256];
    int tid = threadIdx.x;
    int i = blockIdx.x * 256 + tid;
    int v = (i < N) ? deg[i] : 0;
    s[tid] = v;
    __syncthreads();
    for (int off = 1; off < 256; off <<= 1) {
        int t = (tid >= off) ? s[tid - off] : 0;
        __syncthreads();
        s[tid] += t;
        __syncthreads();
    }
    if (i < N) tmp[i] = s[tid];
    if (tid == 255) bsum[blockIdx.x] = s[255];
}
__global__ void k_scan2(const int* __restrict__ bsum, int* __restrict__ boff, int nb) {
    __shared__ int s[1024];
    int tid = threadIdx.x;
    int v = (tid < nb) ? bsum[tid] : 0;
    s[tid] = v;
    __syncthreads();
    for (int off = 1; off < 1024; off <<= 1) {
        int t = (tid >= off) ? s[tid - off] : 0;
        __syncthreads();
        s[tid] += t;
        __syncthreads();
    }
    if (tid < nb) boff[tid] = s[tid] - v;   // exclusive
}
__global__ void k_scan3(const int* __restrict__ tmp, const int* __restrict__ boff,
                        int* __restrict__ row_ptr, int N) {
    int i = blockIdx.x * blockDim.x + threadIdx.x;
    if (i == 0) row_ptr[0] = 0;
    if (i < N) row_ptr[i + 1] = tmp[i] + boff[i >> 8];
}

// ---------------- CSR scatter; stores src, dst, eid per csr slot ----------------
__global__ void k_csr(const int* __restrict__ src, const int* __restrict__ dst,
                      const int* __restrict__ row_ptr, int* __restrict__ cursor,
                      int* __restrict__ csr_src, int* __restrict__ csr_dst,
                      int* __restrict__ csr_eid, int E, int N) {
    int e = blockIdx.x * blockDim.x + threadIdx.x;
    if (e >= E) return;
    int d = clampi(dst[e], N);
    int pos = row_ptr[d] + atomicAdd(&cursor[d], 1);
    if (pos < E) {
        csr_src[pos] = clampi(src[e], N);
        csr_dst[pos] = d;
        csr_eid[pos] = e;
    }
}

// ---------------- graph node counts — LDS histogram ----------------
#define MAXB 2048
__global__ void k_gse(const int* __restrict__ batch, int* __restrict__ gcnt, int N, int B) {
    __shared__ int s_cnt[MAXB];
    int t = threadIdx.x;
    int Bc = B < MAXB ? B : MAXB;
    for (int i = t; i < Bc; i += blockDim.x) s_cnt[i] = 0;
    __syncthreads();
    int n = blockIdx.x * blockDim.x + t;
    if (n < N) {
        int b = clampi(batch[n], B);
        if (b < MAXB) atomicAdd(&s_cnt[b], 1);
        else atomicAdd(&gcnt[b], 1);
    }
    __syncthreads();
    for (int i = t; i < Bc; i += blockDim.x)
        if (s_cnt[i] != 0) atomicAdd(&gcnt[i], s_cnt[i]);
}

// ---------------- ONCE: a_ed for all 3 layers x 4 heads, CSR order ----------------
// aed[j*12 + l*4 + h] = dot(relu(edge_attr[eid(j)] @ eemb_W + b), wred[l][h])
// relu_vec is layer-independent -> one pass computes all 12 dots (vs 3 passes
// of 512 FMA/edge in the old per-layer k_w).
__global__ __launch_bounds__(256) void k_ee(
    const float* __restrict__ edge_attr, const float* __restrict__ eW,
    const float* __restrict__ eB, const float* __restrict__ lin_eW,
    const float* __restrict__ att_e, const int* __restrict__ csr_eid,
    float* __restrict__ aed, int E) {
    __shared__ float s_ew[256];    // [k*64+d]
    __shared__ float s_eb[64];
    __shared__ float s_wred[768];  // [l*256 + h*64 + d]
    int t = threadIdx.x;
    s_ew[t] = eW[t];
    if (t < 64) s_eb[t] = eB[t];
    for (int idx = t; idx < 768; idx += 256) {
        int l = idx >> 8, hd = idx & 255, hh = hd >> 6, d = hd & 63;
        const float* We = lin_eW + (size_t)l * HD * 256;
        const float* ae = att_e + (size_t)l * 256;
        float acc = 0.f;
        for (int c = 0; c < 64; c++)
            acc = fmaf(We[d * 256 + hh * 64 + c], ae[hh * 64 + c], acc);
        s_wred[idx] = acc;
    }
    __syncthreads();
    int j = blockIdx.x * blockDim.x + t;
    if (j >= E) return;
    int e = csr_eid[j];
    float4 a = *(const float4*)(edge_attr + (size_t)e * 4);
    float acc[12];
    #pragma unroll
    for (int m = 0; m < 12; m++) acc[m] = 0.f;
    for (int k = 0; k < HD; k++) {
        float v = fmaf(a.x, s_ew[k], fmaf(a.y, s_ew[64 + k],
                  fmaf(a.z, s_ew[128 + k], fmaf(a.w, s_ew[192 + k], s_eb[k]))));
        v = fmaxf(v, 0.f);
        #pragma unroll
        for (int m = 0; m < 12; m++)
            acc[m] = fmaf(v, s_wred[(m >> 2) * 256 + (m & 3) * 64 + k], acc[m]);
    }
    float* o = aed + (size_t)j * 12;
    #pragma unroll
    for (int m = 0; m < 12; m++) o[m] = acc[m];
}

// ---------------- ONCE: self-loop a_ed rows by LINEARITY ----------------
// dot(mean of relu_vecs, wred) == mean of dots -> self a_ed = row-mean of aed.
// (Replaces k_eaself + ea_self array entirely.)
__global__ void k_selfed(const int* __restrict__ row_ptr, float* __restrict__ aed,
                         int E, int N) {
    int n = blockIdx.x * blockDim.x + threadIdx.x;
    if (n >= N) return;
    int r0 = row_ptr[n], r1 = row_ptr[n + 1];
    float acc[12];
    #pragma unroll
    for (int m = 0; m < 12; m++) acc[m] = 0.f;
    for (int j = r0; j < r1; j++) {
        const float* p = aed + (size_t)j * 12;
        #pragma unroll
        for (int m = 0; m < 12; m++) acc[m] += p[m];
    }
    float inv = 1.f / fmaxf((float)(r1 - r0), 1.f);
    float* o = aed + (size_t)(E + n) * 12;
    #pragma unroll
    for (int m = 0; m < 12; m++) o[m] = acc[m] * inv;
}

// ---------------- per-layer: xp = h@W, 8 nodes per block ----------------
__global__ __launch_bounds__(256) void k_xp(
    const float* __restrict__ h, const float* __restrict__ W,
    const float* __restrict__ asrc, const float* __restrict__ adst,
    u16* __restrict__ xp, float* __restrict__ a_s, float* __restrict__ a_d, int N) {
    __shared__ float hs[8 * HD];
    int n0 = blockIdx.x * 8;
    int t = threadIdx.x;
    for (int i = t; i < 8 * HD; i += 256) {
        int nn = n0 + (i >> 6);
        hs[i] = (nn < N) ? h[(size_t)nn * HD + (i & 63)] : 0.f;
    }
    __syncthreads();
    int c = t;
    float acc[8];
    #pragma unroll
    for (int k = 0; k < 8; k++) acc[k] = 0.f;
    for (int d = 0; d < HD; d++) {
        float wv = W[d * 256 + c];
        #pragma unroll
        for (int k = 0; k < 8; k++) acc[k] = fmaf(hs[k * HD + d], wv, acc[k]);
    }
    float as_ = asrc[c], ad_ = adst[c];
    int hh = c >> 6, cc = c & 63;
    #pragma unroll
    for (int k = 0; k < 8; k++) {
        int nn = n0 + k;
        float ps = acc[k] * as_;
        float pd = acc[k] * ad_;
        #pragma unroll
        for (int o = 32; o > 0; o >>= 1) {
            ps += __shfl_xor(ps, o);
            pd += __shfl_xor(pd, o);
        }
        if (nn < N) {
            xp[(size_t)nn * 256 + c] = f2bf(acc[k]);
            if (cc == 0) { a_s[nn * 4 + hh] = ps; a_d[nn * 4 + hh] = pd; }
        }
    }
}

// ---------------- per-layer: attention weights (lite) ----------------
// Sequential aed/csr_dst reads, random L2 a_s read, 4 exp, coalesced write.
__global__ void k_w(const int* __restrict__ csr_src, const int* __restrict__ csr_dst,
                    const float* __restrict__ aed, const float* __restrict__ a_s,
                    const float* __restrict__ a_d, float* __restrict__ wcsr,
                    int layer, int E, int N) {
    int j = blockIdx.x * blockDim.x + threadIdx.x;
    if (j >= E + N) return;
    int s, d;
    if (j < E) { s = csr_src[j]; d = csr_dst[j]; }
    else       { s = j - E; d = s; }
    const float* p = aed + (size_t)j * 12 + layer * 4;
    float4 as4 = *(const float4*)(a_s + s * 4);
    float4 ad4 = *(const float4*)(a_d + d * 4);
    float w0 = __expf(lrelu(as4.x + ad4.x + p[0]));
    float w1 = __expf(lrelu(as4.y + ad4.y + p[1]));
    float w2 = __expf(lrelu(as4.z + ad4.z + p[2]));
    float w3 = __expf(lrelu(as4.w + ad4.w + p[3]));
    *(float4*)(wcsr + (size_t)j * 4) = make_float4(w0, w1, w2, w3);
}

// ---------------- per-layer GAT aggregate: edge-parallel within wave ----------------
__global__ __launch_bounds__(256) void k_gat(
    const u16* __restrict__ xp, const float* __restrict__ wcsr,
    const int* __restrict__ row_ptr, const int* __restrict__ csr_src,
    const float* __restrict__ convb, float* __restrict__ h_out, int N, int E) {
    int wave = threadIdx.x >> 6, lane = threadIdx.x & 63;
    int n = blockIdx.x * 4 + wave;
    if (n >= N) return;
    int g = lane >> 4, p = lane & 15;
    int r0 = row_ptr[n], r1 = row_ptr[n + 1];
    float a00 = 0.f, a01 = 0.f, a02 = 0.f, a03 = 0.f;
    float a10 = 0.f, a11 = 0.f, a12 = 0.f, a13 = 0.f;
    float a20 = 0.f, a21 = 0.f, a22 = 0.f, a23 = 0.f;
    float a30 = 0.f, a31 = 0.f, a32 = 0.f, a33 = 0.f;
    float d0 = 0.f, d1 = 0.f, d2 = 0.f, d3 = 0.f;
    if (g == 0) {
        float4 w = *(const float4*)(wcsr + (size_t)(E + n) * 4);
        const u16* row = xp + (size_t)n * 256 + p * 4;
        ushort4 v0 = *(const ushort4*)(row);
        ushort4 v1 = *(const ushort4*)(row + 64);
        ushort4 v2 = *(const ushort4*)(row + 128);
        ushort4 v3 = *(const ushort4*)(row + 192);
        d0 += w.x; d1 += w.y; d2 += w.z; d3 += w.w;
        a00 = fmaf(w.x, bf2f(v0.x), a00); a01 = fmaf(w.x, bf2f(v0.y), a01);
        a02 = fmaf(w.x, bf2f(v0.z), a02); a03 = fmaf(w.x, bf2f(v0.w), a03);
        a10 = fmaf(w.y, bf2f(v1.x), a10); a11 = fmaf(w.y, bf2f(v1.y), a11);
        a12 = fmaf(w.y, bf2f(v1.z), a12); a13 = fmaf(w.y, bf2f(v1.w), a13);
        a20 = fmaf(w.z, bf2f(v2.x), a20); a21 = fmaf(w.z, bf2f(v2.y), a21);
        a22 = fmaf(w.z, bf2f(v2.z), a22); a23 = fmaf(w.z, bf2f(v2.w), a23);
        a30 = fmaf(w.w, bf2f(v3.x), a30); a31 = fmaf(w.w, bf2f(v3.y), a31);
        a32 = fmaf(w.w, bf2f(v3.z), a32); a33 = fmaf(w.w, bf2f(v3.w), a33);
    }
    for (int j = r0 + g; j < r1; j += 4) {
        float4 w = *(const float4*)(wcsr + (size_t)j * 4);
        const u16* row = xp + (size_t)csr_src[j] * 256 + p * 4;
        ushort4 v0 = *(const ushort4*)(row);
        ushort4 v1 = *(const ushort4*)(row + 64);
        ushort4 v2 = *(const ushort4*)(row + 128);
        ushort4 v3 = *(const ushort4*)(row + 192);
        d0 += w.x; d1 += w.y; d2 += w.z; d3 += w.w;
        a00 = fmaf(w.x, bf2f(v0.x), a00); a01 = fmaf(w.x, bf2f(v0.y), a01);
        a02 = fmaf(w.x, bf2f(v0.z), a02); a03 = fmaf(w.x, bf2f(v0.w), a03);
        a10 = fmaf(w.y, bf2f(v1.x), a10); a11 = fmaf(w.y, bf2f(v1.y), a11);
        a12 = fmaf(w.y, bf2f(v1.z), a12); a13 = fmaf(w.y, bf2f(v1.w), a13);
        a20 = fmaf(w.z, bf2f(v2.x), a20); a21 = fmaf(w.z, bf2f(v2.y), a21);
        a22 = fmaf(w.z, bf2f(v2.z), a22); a23 = fmaf(w.z, bf2f(v2.w), a23);
        a30 = fmaf(w.w, bf2f(v3.x), a30); a31 = fmaf(w.w, bf2f(v3.y), a31);
        a32 = fmaf(w.w, bf2f(v3.z), a32); a33 = fmaf(w.w, bf2f(v3.w), a33);
    }
    d0 += __shfl_xor(d0, 16); d0 += __shfl_xor(d0, 32);
    d1 += __shfl_xor(d1, 16); d1 += __shfl_xor(d1, 32);
    d2 += __shfl_xor(d2, 16); d2 += __shfl_xor(d2, 32);
    d3 += __shfl_xor(d3, 16); d3 += __shfl_xor(d3, 32);
    float i0 = 1.f / d0, i1 = 1.f / d1, i2 = 1.f / d2, i3 = 1.f / d3;
    float m0 = a00 * i0 + a10 * i1 + a20 * i2 + a30 * i3;
    float m1 = a01 * i0 + a11 * i1 + a21 * i2 + a31 * i3;
    float m2 = a02 * i0 + a12 * i1 + a22 * i2 + a32 * i3;
    float m3 = a03 * i0 + a13 * i1 + a23 * i2 + a33 * i3;
    m0 += __shfl_xor(m0, 16); m0 += __shfl_xor(m0, 32);
    m1 += __shfl_xor(m1, 16); m1 += __shfl_xor(m1, 32);
    m2 += __shfl_xor(m2, 16); m2 += __shfl_xor(m2, 32);
    m3 += __shfl_xor(m3, 16); m3 += __shfl_xor(m3, 32);
    if (lane < 16) {
        int c = p * 4;
        h_out[(size_t)n * HD + c + 0] = fmaxf(0.25f * m0 + convb[c + 0], 0.f);
        h_out[(size_t)n * HD + c + 1] = fmaxf(0.25f * m1 + convb[c + 1], 0.f);
        h_out[(size_t)n * HD + c + 2] = fmaxf(0.25f * m2 + convb[c + 2], 0.f);
        h_out[(size_t)n * HD + c + 3] = fmaxf(0.25f * m3 + convb[c + 3], 0.f);
    }
}

// ---------------- global pool, node-parallel with atomics ----------------
__global__ void k_pool(const float* __restrict__ h, const int* __restrict__ batch,
                       float* __restrict__ pooled, int N, int B) {
    int i = blockIdx.x * blockDim.x + threadIdx.x;
    if (i >= N * HD) return;
    int n = i >> 6, c = i & 63;
    int b = clampi(batch[n], B);
    atomicAdd(&pooled[b * HD + c], h[i]);
}

// ---------------- final MLP (fp32 out; divides pooled sum by count) ----------------
__global__ void k_mlp(const float* __restrict__ u, const float* __restrict__ gW,
                      const float* __restrict__ gb, const float* __restrict__ pooled,
                      const int* __restrict__ gcnt, const float* __restrict__ f1W,
                      const float* __restrict__ f1b, const float* __restrict__ f2W,
                      const float* __restrict__ f2b, float* __restrict__ out, int B) {
    __shared__ float z[2 * HD];
    __shared__ float z1s[HD];
    int b = blockIdx.x, t = threadIdx.x;  // 64 threads
    float acc = gb[t];
    for (int k = 0; k < 10; k++) acc = fmaf(u[b * 10 + k], gW[k * HD + t], acc);
    z[HD + t] = fmaxf(acc, 0.f);
    float invc = 1.f / fmaxf((float)gcnt[b], 1.f);
    z[t] = pooled[b * HD + t] * invc;
    __syncthreads();
    float a1 = f1b[t];
    for (int k = 0; k < 2 * HD; k++) a1 = fmaf(z[k], f1W[k * HD + t], a1);
    z1s[t] = fmaxf(a1, 0.f);
    __syncthreads();
    if (t < 2) {
        float o = f2b[t];
        for (int k = 0; k < HD; k++) o = fmaf(z1s[k], f2W[k * 2 + t], o);
        out[b * 2 + t] = o;
    }
}

extern "C" void kernel_launch(void* const* d_in, const int* in_sizes, int n_in,
                              void* d_out, int out_size, void* d_ws, size_t ws_size,
                              hipStream_t stream) {
    const float* x         = (const float*)d_in[0];
    const int*   ei        = (const int*)d_in[1];
    const float* edge_attr = (const float*)d_in[2];
    const float* u         = (const float*)d_in[3];
    const int*   batch     = (const int*)d_in[4];
    const float* node_W    = (const float*)d_in[5];
    const float* node_b    = (const float*)d_in[6];
    const float* eemb_W    = (const float*)d_in[7];
    const float* eemb_b    = (const float*)d_in[8];
    const float* lin_W     = (const float*)d_in[9];
    const float* att_src   = (const float*)d_in[10];
    const float* att_dst   = (const float*)d_in[11];
    const float* lin_eW    = (const float*)d_in[12];
    const float* att_e     = (const float*)d_in[13];
    const float* conv_b    = (const float*)d_in[14];
    const float* gW        = (const float*)d_in[15];
    const float* gb        = (const float*)d_in[16];
    const float* f1W       = (const float*)d_in[17];
    const float* f1b       = (const float*)d_in[18];
    const float* f2W       = (const float*)d_in[19];
    const float* f2b       = (const float*)d_in[20];

    const int N = in_sizes[0] / 3;
    const int E = in_sizes[2] / 4;
    const int B = in_sizes[3] / 10;
    const int* src = ei;
    const int* dst = ei + E;
    const int NB = (N + 255) / 256;   // scan blocks

    // workspace carve (fp32 then bf16 then ints)
    float* wsf = (float*)d_ws;
    float* h       = wsf;              wsf += (size_t)N * HD;
    float* a_s     = wsf;              wsf += (size_t)N * 4;
    float* a_d     = wsf;              wsf += (size_t)N * 4;
    float* aed     = wsf;              wsf += (size_t)(E + N) * 12;
    float* wcsr    = wsf;              wsf += (size_t)(E + N) * 4;
    float* pooled  = wsf;              wsf += (size_t)B * HD;
    u16* xp = (u16*)wsf;               wsf += (size_t)N * 128;   // N*256 bf16
    int* wsi = (int*)wsf;
    int* deg     = wsi;                wsi += N;
    int* row_ptr = wsi;                wsi += N + 1;
    int* cursor  = wsi;                wsi += N;
    int* tmp     = wsi;                wsi += N;
    int* bsum    = wsi;                wsi += NB + 1;
    int* boff    = wsi;                wsi += NB + 1;
    int* csr_src = wsi;                wsi += E;
    int* csr_dst = wsi;                wsi += E;
    int* csr_eid = wsi;                wsi += E;
    int* gcnt    = wsi;                wsi += B;

    k_init<<<NB, 256, 0, stream>>>(deg, cursor, gcnt, pooled, N, B);
    k_node_emb<<<(N * HD + 255) / 256, 256, 0, stream>>>(x, node_W, node_b, h, N);
    k_deg<<<(E + 255) / 256, 256, 0, stream>>>(dst, deg, E, N);
    k_scan1<<<NB, 256, 0, stream>>>(deg, tmp, bsum, N);
    k_scan2<<<1, 1024, 0, stream>>>(bsum, boff, NB);
    k_scan3<<<NB, 256, 0, stream>>>(tmp, boff, row_ptr, N);
    k_csr<<<(E + 255) / 256, 256, 0, stream>>>(src, dst, row_ptr, cursor,
                                               csr_src, csr_dst, csr_eid, E, N);
    k_gse<<<NB, 256, 0, stream>>>(batch, gcnt, N, B);
    k_ee<<<(E + 255) / 256, 256, 0, stream>>>(edge_attr, eemb_W, eemb_b, lin_eW, att_e,
                                              csr_eid, aed, E);
    k_selfed<<<NB, 256, 0, stream>>>(row_ptr, aed, E, N);
    for (int i = 0; i < 3; i++) {
        k_xp<<<(N + 7) / 8, 256, 0, stream>>>(h, lin_W + (size_t)i * HD * 256,
                                              att_src + (size_t)i * 256,
                                              att_dst + (size_t)i * 256,
                                              xp, a_s, a_d, N);
        k_w<<<(E + N + 255) / 256, 256, 0, stream>>>(csr_src, csr_dst, aed, a_s, a_d,
                                                     wcsr, i, E, N);
        k_gat<<<(N + 3) / 4, 256, 0, stream>>>(xp, wcsr, row_ptr, csr_src,
                                               conv_b + (size_t)i * HD, h, N, E);
    }
    k_pool<<<(N * HD + 255) / 256, 256, 0, stream>>>(h, batch, pooled, N, B);
    k_mlp<<<B, 64, 0, stream>>>(u, gW, gb, pooled, gcnt, f1W, f1b, f2W, f2b,
                                (float*)d_out, B);
}

// Round 17
// 411.518 us; speedup vs baseline: 1.7294x; 1.0266x over previous
//
#include <hip/hip_runtime.h>
#include <hip/hip_bf16.h>

#define HD 64

typedef unsigned short u16;

__device__ __forceinline__ float lrelu(float x) { return x > 0.f ? x : 0.2f * x; }
__device__ __forceinline__ int clampi(int v, int maxv) {
    return v < 0 ? 0 : (v >= maxv ? maxv - 1 : v);
}
__device__ __forceinline__ float bf2f(u16 u) {
    return __uint_as_float(((unsigned int)u) << 16);
}
// round-to-nearest-even fp32 -> bf16 (bit-level; inputs are finite)
__device__ __forceinline__ u16 f2bf(float f) {
    unsigned int u = __float_as_uint(f);
    unsigned int lsb = (u >> 16) & 1u;
    u += 0x7fffu + lsb;
    return (u16)(u >> 16);
}

// ---------------- init: zero deg/cursor/pooled/gcnt ----------------
__global__ void k_init(int* deg, int* cursor, int* gcnt, float* pooled, int N, int B) {
    int i = blockIdx.x * blockDim.x + threadIdx.x;
    if (i < N) { deg[i] = 0; cursor[i] = 0; }
    if (i < B) gcnt[i] = 0;
    if (i < B * HD) pooled[i] = 0.f;
}

// ---------------- h = relu(x @ node_W + node_b),  x:[N,3] W:[3,64] ----------------
__global__ void k_node_emb(const float* __restrict__ x, const float* __restrict__ W,
                           const float* __restrict__ b, float* __restrict__ h, int N) {
    int i = blockIdx.x * blockDim.x + threadIdx.x;
    if (i >= N * HD) return;
    int n = i >> 6, c = i & 63;
    float acc = b[c];
    acc = fmaf(x[n * 3 + 0], W[0 * HD + c], acc);
    acc = fmaf(x[n * 3 + 1], W[1 * HD + c], acc);
    acc = fmaf(x[n * 3 + 2], W[2 * HD + c], acc);
    h[i] = fmaxf(acc, 0.f);
}

// ---------------- degree histogram over dst ----------------
__global__ void k_deg(const int* __restrict__ dst, int* __restrict__ deg, int E, int N) {
    int e = blockIdx.x * blockDim.x + threadIdx.x;
    if (e < E) atomicAdd(&deg[clampi(dst[e], N)], 1);
}

// ---------------- hierarchical scan ----------------
__global__ void k_scan1(const int* __restrict__ deg, int* __restrict__ tmp,
                        int* __restrict__ bsum, int N) {
    __shared__ int s[256];
    int tid = threadIdx.x;
    int i = blockIdx.x * 256 + tid;
    int v = (i < N) ? deg[i] : 0;
    s[tid] = v;
    __syncthreads();
    for (int off = 1; off < 256; off <<= 1) {
        int t = (tid >= off) ? s[tid - off] : 0;
        __syncthreads();
        s[tid] += t;
        __syncthreads();
    }
    if (i < N) tmp[i] = s[tid];
    if (tid == 255) bsum[blockIdx.x] = s[255];
}
__global__ void k_scan2(const int* __restrict__ bsum, int* __restrict__ boff, int nb) {
    __shared__ int s[1024];
    int tid = threadIdx.x;
    int v = (tid < nb) ? bsum[tid] : 0;
    s[tid] = v;
    __syncthreads();
    for (int off = 1; off < 1024; off <<= 1) {
        int t = (tid >= off) ? s[tid - off] : 0;
        __syncthreads();
        s[tid] += t;
        __syncthreads();
    }
    if (tid < nb) boff[tid] = s[tid] - v;   // exclusive
}
__global__ void k_scan3(const int* __restrict__ tmp, const int* __restrict__ boff,
                        int* __restrict__ row_ptr, int N) {
    int i = blockIdx.x * blockDim.x + threadIdx.x;
    if (i == 0) row_ptr[0] = 0;
    if (i < N) row_ptr[i + 1] = tmp[i] + boff[i >> 8];
}

// ---------------- CSR scatter; stores src, dst, eid per csr slot ----------------
__global__ void k_csr(const int* __restrict__ src, const int* __restrict__ dst,
                      const int* __restrict__ row_ptr, int* __restrict__ cursor,
                      int* __restrict__ csr_src, int* __restrict__ csr_dst,
                      int* __restrict__ csr_eid, int E, int N) {
    int e = blockIdx.x * blockDim.x + threadIdx.x;
    if (e >= E) return;
    int d = clampi(dst[e], N);
    int pos = row_ptr[d] + atomicAdd(&cursor[d], 1);
    if (pos < E) {
        csr_src[pos] = clampi(src[e], N);
        csr_dst[pos] = d;
        csr_eid[pos] = e;
    }
}

// ---------------- graph node counts — LDS histogram ----------------
#define MAXB 2048
__global__ void k_gse(const int* __restrict__ batch, int* __restrict__ gcnt, int N, int B) {
    __shared__ int s_cnt[MAXB];
    int t = threadIdx.x;
    int Bc = B < MAXB ? B : MAXB;
    for (int i = t; i < Bc; i += blockDim.x) s_cnt[i] = 0;
    __syncthreads();
    int n = blockIdx.x * blockDim.x + t;
    if (n < N) {
        int b = clampi(batch[n], B);
        if (b < MAXB) atomicAdd(&s_cnt[b], 1);
        else atomicAdd(&gcnt[b], 1);
    }
    __syncthreads();
    for (int i = t; i < Bc; i += blockDim.x)
        if (s_cnt[i] != 0) atomicAdd(&gcnt[i], s_cnt[i]);
}

// ---------------- ONCE: a_ed for all 3 layers x 4 heads, CSR order ----------------
// 4 edges per thread: the 5 LDS broadcast reads per k are shared across 4 edges
// (R16 version was LDS-read-bound: 17 LDS : 17 FMA per k, VALU 22%).
// Now 5 LDS : 68 FMA per k.
__global__ __launch_bounds__(256) void k_ee(
    const float* __restrict__ edge_attr, const float* __restrict__ eW,
    const float* __restrict__ eB, const float* __restrict__ lin_eW,
    const float* __restrict__ att_e, const int* __restrict__ csr_eid,
    float* __restrict__ aed, int E) {
    __shared__ float s_ew[256];    // [k*64+d]
    __shared__ float s_eb[64];
    __shared__ float s_wred[768];  // [l*256 + h*64 + d]
    int t = threadIdx.x;
    s_ew[t] = eW[t];
    if (t < 64) s_eb[t] = eB[t];
    for (int idx = t; idx < 768; idx += 256) {
        int l = idx >> 8, hd = idx & 255, hh = hd >> 6, d = hd & 63;
        const float* We = lin_eW + (size_t)l * HD * 256;
        const float* ae = att_e + (size_t)l * 256;
        float acc = 0.f;
        for (int c = 0; c < 64; c++)
            acc = fmaf(We[d * 256 + hh * 64 + c], ae[hh * 64 + c], acc);
        s_wred[idx] = acc;
    }
    __syncthreads();
    int j0 = (blockIdx.x * 256 + t) * 4;
    if (j0 >= E) return;
    float4 a[4];
    int nv = 0;
    #pragma unroll
    for (int q = 0; q < 4; q++) {
        int j = j0 + q;
        if (j < E) {
            a[q] = *(const float4*)(edge_attr + (size_t)csr_eid[j] * 4);
            nv = q + 1;
        } else {
            a[q] = make_float4(0.f, 0.f, 0.f, 0.f);
        }
    }
    float acc[4][12];
    #pragma unroll
    for (int q = 0; q < 4; q++)
        #pragma unroll
        for (int m = 0; m < 12; m++) acc[q][m] = 0.f;
    for (int k = 0; k < HD; k++) {
        float e0 = s_ew[k], e1 = s_ew[64 + k], e2 = s_ew[128 + k], e3 = s_ew[192 + k];
        float eb = s_eb[k];
        float w[12];
        #pragma unroll
        for (int m = 0; m < 12; m++)
            w[m] = s_wred[(m >> 2) * 256 + (m & 3) * 64 + k];
        #pragma unroll
        for (int q = 0; q < 4; q++) {
            float v = fmaf(a[q].x, e0, fmaf(a[q].y, e1,
                      fmaf(a[q].z, e2, fmaf(a[q].w, e3, eb))));
            v = fmaxf(v, 0.f);
            #pragma unroll
            for (int m = 0; m < 12; m++) acc[q][m] = fmaf(v, w[m], acc[q][m]);
        }
    }
    #pragma unroll
    for (int q = 0; q < 4; q++) {
        if (q >= nv) break;
        float* o = aed + (size_t)(j0 + q) * 12;
        #pragma unroll
        for (int m = 0; m < 12; m++) o[m] = acc[q][m];
    }
}

// ---------------- ONCE: self-loop a_ed rows by LINEARITY ----------------
__global__ void k_selfed(const int* __restrict__ row_ptr, float* __restrict__ aed,
                         int E, int N) {
    int n = blockIdx.x * blockDim.x + threadIdx.x;
    if (n >= N) return;
    int r0 = row_ptr[n], r1 = row_ptr[n + 1];
    float acc[12];
    #pragma unroll
    for (int m = 0; m < 12; m++) acc[m] = 0.f;
    for (int j = r0; j < r1; j++) {
        const float* p = aed + (size_t)j * 12;
        #pragma unroll
        for (int m = 0; m < 12; m++) acc[m] += p[m];
    }
    float inv = 1.f / fmaxf((float)(r1 - r0), 1.f);
    float* o = aed + (size_t)(E + n) * 12;
    #pragma unroll
    for (int m = 0; m < 12; m++) o[m] = acc[m] * inv;
}

// ---------------- per-layer: xp = h@W, 8 nodes per block ----------------
__global__ __launch_bounds__(256) void k_xp(
    const float* __restrict__ h, const float* __restrict__ W,
    const float* __restrict__ asrc, const float* __restrict__ adst,
    u16* __restrict__ xp, float* __restrict__ a_s, float* __restrict__ a_d, int N) {
    __shared__ float hs[8 * HD];
    int n0 = blockIdx.x * 8;
    int t = threadIdx.x;
    for (int i = t; i < 8 * HD; i += 256) {
        int nn = n0 + (i >> 6);
        hs[i] = (nn < N) ? h[(size_t)nn * HD + (i & 63)] : 0.f;
    }
    __syncthreads();
    int c = t;
    float acc[8];
    #pragma unroll
    for (int k = 0; k < 8; k++) acc[k] = 0.f;
    for (int d = 0; d < HD; d++) {
        float wv = W[d * 256 + c];
        #pragma unroll
        for (int k = 0; k < 8; k++) acc[k] = fmaf(hs[k * HD + d], wv, acc[k]);
    }
    float as_ = asrc[c], ad_ = adst[c];
    int hh = c >> 6, cc = c & 63;
    #pragma unroll
    for (int k = 0; k < 8; k++) {
        int nn = n0 + k;
        float ps = acc[k] * as_;
        float pd = acc[k] * ad_;
        #pragma unroll
        for (int o = 32; o > 0; o >>= 1) {
            ps += __shfl_xor(ps, o);
            pd += __shfl_xor(pd, o);
        }
        if (nn < N) {
            xp[(size_t)nn * 256 + c] = f2bf(acc[k]);
            if (cc == 0) { a_s[nn * 4 + hh] = ps; a_d[nn * 4 + hh] = pd; }
        }
    }
}

// ---------------- per-layer: attention weights (lite) ----------------
__global__ void k_w(const int* __restrict__ csr_src, const int* __restrict__ csr_dst,
                    const float* __restrict__ aed, const float* __restrict__ a_s,
                    const float* __restrict__ a_d, float* __restrict__ wcsr,
                    int layer, int E, int N) {
    int j = blockIdx.x * blockDim.x + threadIdx.x;
    if (j >= E + N) return;
    int s, d;
    if (j < E) { s = csr_src[j]; d = csr_dst[j]; }
    else       { s = j - E; d = s; }
    const float* p = aed + (size_t)j * 12 + layer * 4;
    float4 as4 = *(const float4*)(a_s + s * 4);
    float4 ad4 = *(const float4*)(a_d + d * 4);
    float w0 = __expf(lrelu(as4.x + ad4.x + p[0]));
    float w1 = __expf(lrelu(as4.y + ad4.y + p[1]));
    float w2 = __expf(lrelu(as4.z + ad4.z + p[2]));
    float w3 = __expf(lrelu(as4.w + ad4.w + p[3]));
    *(float4*)(wcsr + (size_t)j * 4) = make_float4(w0, w1, w2, w3);
}

// ---------------- per-layer GAT aggregate: edge-parallel within wave ----------------
__global__ __launch_bounds__(256) void k_gat(
    const u16* __restrict__ xp, const float* __restrict__ wcsr,
    const int* __restrict__ row_ptr, const int* __restrict__ csr_src,
    const float* __restrict__ convb, float* __restrict__ h_out, int N, int E) {
    int wave = threadIdx.x >> 6, lane = threadIdx.x & 63;
    int n = blockIdx.x * 4 + wave;
    if (n >= N) return;
    int g = lane >> 4, p = lane & 15;
    int r0 = row_ptr[n], r1 = row_ptr[n + 1];
    float a00 = 0.f, a01 = 0.f, a02 = 0.f, a03 = 0.f;
    float a10 = 0.f, a11 = 0.f, a12 = 0.f, a13 = 0.f;
    float a20 = 0.f, a21 = 0.f, a22 = 0.f, a23 = 0.f;
    float a30 = 0.f, a31 = 0.f, a32 = 0.f, a33 = 0.f;
    float d0 = 0.f, d1 = 0.f, d2 = 0.f, d3 = 0.f;
    if (g == 0) {
        float4 w = *(const float4*)(wcsr + (size_t)(E + n) * 4);
        const u16* row = xp + (size_t)n * 256 + p * 4;
        ushort4 v0 = *(const ushort4*)(row);
        ushort4 v1 = *(const ushort4*)(row + 64);
        ushort4 v2 = *(const ushort4*)(row + 128);
        ushort4 v3 = *(const ushort4*)(row + 192);
        d0 += w.x; d1 += w.y; d2 += w.z; d3 += w.w;
        a00 = fmaf(w.x, bf2f(v0.x), a00); a01 = fmaf(w.x, bf2f(v0.y), a01);
        a02 = fmaf(w.x, bf2f(v0.z), a02); a03 = fmaf(w.x, bf2f(v0.w), a03);
        a10 = fmaf(w.y, bf2f(v1.x), a10); a11 = fmaf(w.y, bf2f(v1.y), a11);
        a12 = fmaf(w.y, bf2f(v1.z), a12); a13 = fmaf(w.y, bf2f(v1.w), a13);
        a20 = fmaf(w.z, bf2f(v2.x), a20); a21 = fmaf(w.z, bf2f(v2.y), a21);
        a22 = fmaf(w.z, bf2f(v2.z), a22); a23 = fmaf(w.z, bf2f(v2.w), a23);
        a30 = fmaf(w.w, bf2f(v3.x), a30); a31 = fmaf(w.w, bf2f(v3.y), a31);
        a32 = fmaf(w.w, bf2f(v3.z), a32); a33 = fmaf(w.w, bf2f(v3.w), a33);
    }
    for (int j = r0 + g; j < r1; j += 4) {
        float4 w = *(const float4*)(wcsr + (size_t)j * 4);
        const u16* row = xp + (size_t)csr_src[j] * 256 + p * 4;
        ushort4 v0 = *(const ushort4*)(row);
        ushort4 v1 = *(const ushort4*)(row + 64);
        ushort4 v2 = *(const ushort4*)(row + 128);
        ushort4 v3 = *(const ushort4*)(row + 192);
        d0 += w.x; d1 += w.y; d2 += w.z; d3 += w.w;
        a00 = fmaf(w.x, bf2f(v0.x), a00); a01 = fmaf(w.x, bf2f(v0.y), a01);
        a02 = fmaf(w.x, bf2f(v0.z), a02); a03 = fmaf(w.x, bf2f(v0.w), a03);
        a10 = fmaf(w.y, bf2f(v1.x), a10); a11 = fmaf(w.y, bf2f(v1.y), a11);
        a12 = fmaf(w.y, bf2f(v1.z), a12); a13 = fmaf(w.y, bf2f(v1.w), a13);
        a20 = fmaf(w.z, bf2f(v2.x), a20); a21 = fmaf(w.z, bf2f(v2.y), a21);
        a22 = fmaf(w.z, bf2f(v2.z), a22); a23 = fmaf(w.z, bf2f(v2.w), a23);
        a30 = fmaf(w.w, bf2f(v3.x), a30); a31 = fmaf(w.w, bf2f(v3.y), a31);
        a32 = fmaf(w.w, bf2f(v3.z), a32); a33 = fmaf(w.w, bf2f(v3.w), a33);
    }
    d0 += __shfl_xor(d0, 16); d0 += __shfl_xor(d0, 32);
    d1 += __shfl_xor(d1, 16); d1 += __shfl_xor(d1, 32);
    d2 += __shfl_xor(d2, 16); d2 += __shfl_xor(d2, 32);
    d3 += __shfl_xor(d3, 16); d3 += __shfl_xor(d3, 32);
    float i0 = 1.f / d0, i1 = 1.f / d1, i2 = 1.f / d2, i3 = 1.f / d3;
    float m0 = a00 * i0 + a10 * i1 + a20 * i2 + a30 * i3;
    float m1 = a01 * i0 + a11 * i1 + a21 * i2 + a31 * i3;
    float m2 = a02 * i0 + a12 * i1 + a22 * i2 + a32 * i3;
    float m3 = a03 * i0 + a13 * i1 + a23 * i2 + a33 * i3;
    m0 += __shfl_xor(m0, 16); m0 += __shfl_xor(m0, 32);
    m1 += __shfl_xor(m1, 16); m1 += __shfl_xor(m1, 32);
    m2 += __shfl_xor(m2, 16); m2 += __shfl_xor(m2, 32);
    m3 += __shfl_xor(m3, 16); m3 += __shfl_xor(m3, 32);
    if (lane < 16) {
        int c = p * 4;
        h_out[(size_t)n * HD + c + 0] = fmaxf(0.25f * m0 + convb[c + 0], 0.f);
        h_out[(size_t)n * HD + c + 1] = fmaxf(0.25f * m1 + convb[c + 1], 0.f);
        h_out[(size_t)n * HD + c + 2] = fmaxf(0.25f * m2 + convb[c + 2], 0.f);
        h_out[(size_t)n * HD + c + 3] = fmaxf(0.25f * m3 + convb[c + 3], 0.f);
    }
}

// ---------------- global pool, node-parallel with atomics ----------------
__global__ void k_pool(const float* __restrict__ h, const int* __restrict__ batch,
                       float* __restrict__ pooled, int N, int B) {
    int i = blockIdx.x * blockDim.x + threadIdx.x;
    if (i >= N * HD) return;
    int n = i >> 6, c = i & 63;
    int b = clampi(batch[n], B);
    atomicAdd(&pooled[b * HD + c], h[i]);
}

// ---------------- final MLP (fp32 out; divides pooled sum by count) ----------------
__global__ void k_mlp(const float* __restrict__ u, const float* __restrict__ gW,
                      const float* __restrict__ gb, const float* __restrict__ pooled,
                      const int* __restrict__ gcnt, const float* __restrict__ f1W,
                      const float* __restrict__ f1b, const float* __restrict__ f2W,
                      const float* __restrict__ f2b, float* __restrict__ out, int B) {
    __shared__ float z[2 * HD];
    __shared__ float z1s[HD];
    int b = blockIdx.x, t = threadIdx.x;  // 64 threads
    float acc = gb[t];
    for (int k = 0; k < 10; k++) acc = fmaf(u[b * 10 + k], gW[k * HD + t], acc);
    z[HD + t] = fmaxf(acc, 0.f);
    float invc = 1.f / fmaxf((float)gcnt[b], 1.f);
    z[t] = pooled[b * HD + t] * invc;
    __syncthreads();
    float a1 = f1b[t];
    for (int k = 0; k < 2 * HD; k++) a1 = fmaf(z[k], f1W[k * HD + t], a1);
    z1s[t] = fmaxf(a1, 0.f);
    __syncthreads();
    if (t < 2) {
        float o = f2b[t];
        for (int k = 0; k < HD; k++) o = fmaf(z1s[k], f2W[k * 2 + t], o);
        out[b * 2 + t] = o;
    }
}

extern "C" void kernel_launch(void* const* d_in, const int* in_sizes, int n_in,
                              void* d_out, int out_size, void* d_ws, size_t ws_size,
                              hipStream_t stream) {
    const float* x         = (const float*)d_in[0];
    const int*   ei        = (const int*)d_in[1];
    const float* edge_attr = (const float*)d_in[2];
    const float* u         = (const float*)d_in[3];
    const int*   batch     = (const int*)d_in[4];
    const float* node_W    = (const float*)d_in[5];
    const float* node_b    = (const float*)d_in[6];
    const float* eemb_W    = (const float*)d_in[7];
    const float* eemb_b    = (const float*)d_in[8];
    const float* lin_W     = (const float*)d_in[9];
    const float* att_src   = (const float*)d_in[10];
    const float* att_dst   = (const float*)d_in[11];
    const float* lin_eW    = (const float*)d_in[12];
    const float* att_e     = (const float*)d_in[13];
    const float* conv_b    = (const float*)d_in[14];
    const float* gW        = (const float*)d_in[15];
    const float* gb        = (const float*)d_in[16];
    const float* f1W       = (const float*)d_in[17];
    const float* f1b       = (const float*)d_in[18];
    const float* f2W       = (const float*)d_in[19];
    const float* f2b       = (const float*)d_in[20];

    const int N = in_sizes[0] / 3;
    const int E = in_sizes[2] / 4;
    const int B = in_sizes[3] / 10;
    const int* src = ei;
    const int* dst = ei + E;
    const int NB = (N + 255) / 256;   // scan blocks

    // workspace carve (fp32 then bf16 then ints)
    float* wsf = (float*)d_ws;
    float* h       = wsf;              wsf += (size_t)N * HD;
    float* a_s     = wsf;              wsf += (size_t)N * 4;
    float* a_d     = wsf;              wsf += (size_t)N * 4;
    float* aed     = wsf;              wsf += (size_t)(E + N) * 12;
    float* wcsr    = wsf;              wsf += (size_t)(E + N) * 4;
    float* pooled  = wsf;              wsf += (size_t)B * HD;
    u16* xp = (u16*)wsf;               wsf += (size_t)N * 128;   // N*256 bf16
    int* wsi = (int*)wsf;
    int* deg     = wsi;                wsi += N;
    int* row_ptr = wsi;                wsi += N + 1;
    int* cursor  = wsi;                wsi += N;
    int* tmp     = wsi;                wsi += N;
    int* bsum    = wsi;                wsi += NB + 1;
    int* boff    = wsi;                wsi += NB + 1;
    int* csr_src = wsi;                wsi += E;
    int* csr_dst = wsi;                wsi += E;
    int* csr_eid = wsi;                wsi += E;
    int* gcnt    = wsi;                wsi += B;

    k_init<<<NB, 256, 0, stream>>>(deg, cursor, gcnt, pooled, N, B);
    k_node_emb<<<(N * HD + 255) / 256, 256, 0, stream>>>(x, node_W, node_b, h, N);
    k_deg<<<(E + 255) / 256, 256, 0, stream>>>(dst, deg, E, N);
    k_scan1<<<NB, 256, 0, stream>>>(deg, tmp, bsum, N);
    k_scan2<<<1, 1024, 0, stream>>>(bsum, boff, NB);
    k_scan3<<<NB, 256, 0, stream>>>(tmp, boff, row_ptr, N);
    k_csr<<<(E + 255) / 256, 256, 0, stream>>>(src, dst, row_ptr, cursor,
                                               csr_src, csr_dst, csr_eid, E, N);
    k_gse<<<NB, 256, 0, stream>>>(batch, gcnt, N, B);
    k_ee<<<(E + 1023) / 1024, 256, 0, stream>>>(edge_attr, eemb_W, eemb_b, lin_eW, att_e,
                                                csr_eid, aed, E);
    k_selfed<<<NB, 256, 0, stream>>>(row_ptr, aed, E, N);
    for (int i = 0; i < 3; i++) {
        k_xp<<<(N + 7) / 8, 256, 0, stream>>>(h, lin_W + (size_t)i * HD * 256,
                                              att_src + (size_t)i * 256,
                                              att_dst + (size_t)i * 256,
                                              xp, a_s, a_d, N);
        k_w<<<(E + N + 255) / 256, 256, 0, stream>>>(csr_src, csr_dst, aed, a_s, a_d,
                                                     wcsr, i, E, N);
        k_gat<<<(N + 3) / 4, 256, 0, stream>>>(xp, wcsr, row_ptr, csr_src,
                                               conv_b + (size_t)i * HD, h, N, E);
    }
    k_pool<<<(N * HD + 255) / 256, 256, 0, stream>>>(h, batch, pooled, N, B);
    k_mlp<<<B, 64, 0, stream>>>(u, gW, gb, pooled, gcnt, f1W, f1b, f2W, f2b,
                                (float*)d_out, B);
}